// Round 2
// baseline (651.967 us; speedup 1.0000x reference)
//
#include <hip/hip_runtime.h>
#include <cstdint>
#include <cstddef>

typedef unsigned short u16;
typedef __bf16 bf16_t;
typedef bf16_t bf16x8 __attribute__((ext_vector_type(8)));
typedef float f32x4 __attribute__((ext_vector_type(4)));

static __device__ __forceinline__ float bf2f(u16 v) {
    union { unsigned int u; float f; } cv;
    cv.u = ((unsigned int)v) << 16;
    return cv.f;
}
static __device__ __forceinline__ u16 f2bf(float f) {
    union { float f; unsigned int u; } cv;
    cv.f = f;
    unsigned int r = 0x7fffu + ((cv.u >> 16) & 1u);
    return (u16)((cv.u + r) >> 16);
}

// ---------------------------------------------------------------------------
// fp32 -> bf16 conversion (weights), 4 elems/thread
// ---------------------------------------------------------------------------
__global__ __launch_bounds__(256)
void f2bf_kernel(const float* __restrict__ in, u16* __restrict__ out, int n4)
{
    const int i = blockIdx.x * 256 + threadIdx.x;
    if (i < n4) {
        float4 f = ((const float4*)in)[i];
        ushort4 o;
        o.x = f2bf(f.x); o.y = f2bf(f.y); o.z = f2bf(f.z); o.w = f2bf(f.w);
        ((ushort4*)out)[i] = o;
    }
}

// ---------------------------------------------------------------------------
// LayerNorm over rows of 1024, fp32 in (x or x2), bf16 out. 256 thr/row.
// ---------------------------------------------------------------------------
__global__ __launch_bounds__(256)
void ln_kernel(const float* __restrict__ xin, const float* __restrict__ w,
               const float* __restrict__ b, u16* __restrict__ out)
{
    const int row = blockIdx.x;
    const int tid = threadIdx.x;
    const float4 f = ((const float4*)(xin + (size_t)row * 1024))[tid];
    float vals[4] = { f.x, f.y, f.z, f.w };
    float s  = vals[0] + vals[1] + vals[2] + vals[3];
    float ss = vals[0]*vals[0] + vals[1]*vals[1] + vals[2]*vals[2] + vals[3]*vals[3];
    for (int off = 32; off; off >>= 1) {
        s  += __shfl_down(s, off, 64);
        ss += __shfl_down(ss, off, 64);
    }
    __shared__ float redS[4], redQ[4];
    if ((tid & 63) == 0) { redS[tid >> 6] = s; redQ[tid >> 6] = ss; }
    __syncthreads();
    s  = redS[0] + redS[1] + redS[2] + redS[3];
    ss = redQ[0] + redQ[1] + redQ[2] + redQ[3];
    const float mu  = s * (1.f / 1024.f);
    const float var = ss * (1.f / 1024.f) - mu * mu;
    const float rs  = rsqrtf(var + 1e-5f);
    const float4 wv = ((const float4*)w)[tid];
    const float4 bv = ((const float4*)b)[tid];
    ushort4 o;
    o.x = f2bf((vals[0] - mu) * rs * wv.x + bv.x);
    o.y = f2bf((vals[1] - mu) * rs * wv.y + bv.y);
    o.z = f2bf((vals[2] - mu) * rs * wv.z + bv.z);
    o.w = f2bf((vals[3] - mu) * rs * wv.w + bv.w);
    ((ushort4*)(out + (size_t)row * 1024))[tid] = o;
}

// ---------------------------------------------------------------------------
// GEMM: out[M,N] = A[M,K] @ B[N,K]^T  (bf16 in, K contiguous), m97 recipe:
// 128x128 tile, BK=64, 4 waves (2x2 of 64x64), mfma_f32_16x16x32_bf16,
// global_load_lds width=16 staging.
// EPI: 0: bf16(acc)            -> u16*
//      1: f32(aux1) + acc      -> float*   (residual add, aux1 = x fp32)
//      2: bf16(relu(acc)^2)    -> u16*
//      3: bf16(sigmoid(acc))   -> u16*
//      4: f32(aux1) + bf16(aux2)*acc -> float*  (final residual)
// ---------------------------------------------------------------------------
template<int EPI>
__global__ __launch_bounds__(256)
void gemm_bt(const u16* __restrict__ A, const u16* __restrict__ B,
             int M, int N, int K,
             void* __restrict__ outp,
             const void* __restrict__ aux1, const void* __restrict__ aux2)
{
    __shared__ u16 lA[128 * 64];
    __shared__ u16 lB[128 * 64];
    const int tid  = threadIdx.x;
    const int wave = tid >> 6;
    const int lane = tid & 63;
    const int q    = lane >> 4;
    const int l16  = lane & 15;
    const long mBase = (long)blockIdx.y * 128;
    const long nBase = (long)blockIdx.x * 128;
    const int wm = (wave >> 1) * 64;
    const int wn = (wave & 1) * 64;

    f32x4 acc[4][4];
#pragma unroll
    for (int i = 0; i < 4; ++i)
#pragma unroll
        for (int j = 0; j < 4; ++j)
#pragma unroll
            for (int r = 0; r < 4; ++r) acc[i][j][r] = 0.f;

    // staging: element e = (c*256+tid)*8 of the 128x64 tile; row=e/64, col=e%64
    const int srow = tid >> 3;
    const int scol = (tid & 7) * 8;
    const int ldsW = wave * 512;   // wave-uniform LDS element offset within chunk

    for (int kb = 0; kb < K; kb += 64) {
        __syncthreads();
#pragma unroll
        for (int c = 0; c < 4; ++c) {
            const int row = c * 32 + srow;
            const u16* ga = A + (mBase + row) * (long)K + kb + scol;
            const u16* gb = B + (nBase + row) * (long)K + kb + scol;
            __builtin_amdgcn_global_load_lds(
                (const __attribute__((address_space(1))) void*)ga,
                (__attribute__((address_space(3))) void*)(lA + c * 2048 + ldsW),
                16, 0, 0);
            __builtin_amdgcn_global_load_lds(
                (const __attribute__((address_space(1))) void*)gb,
                (__attribute__((address_space(3))) void*)(lB + c * 2048 + ldsW),
                16, 0, 0);
        }
        __syncthreads();
#pragma unroll
        for (int ks = 0; ks < 2; ++ks) {
            bf16x8 af[4], bfm[4];
#pragma unroll
            for (int i = 0; i < 4; ++i) {
                af[i]  = *(const bf16x8*)(lA + (wm + i * 16 + l16) * 64 + ks * 32 + q * 8);
                bfm[i] = *(const bf16x8*)(lB + (wn + i * 16 + l16) * 64 + ks * 32 + q * 8);
            }
#pragma unroll
            for (int i = 0; i < 4; ++i)
#pragma unroll
                for (int j = 0; j < 4; ++j)
                    acc[i][j] = __builtin_amdgcn_mfma_f32_16x16x32_bf16(
                        af[i], bfm[j], acc[i][j], 0, 0, 0);
        }
    }

    // epilogue: C/D layout col=lane&15, row=(lane>>4)*4+reg  [m89/m91]
    const long colBase = nBase + wn + l16;
#pragma unroll
    for (int i = 0; i < 4; ++i) {
#pragma unroll
        for (int r = 0; r < 4; ++r) {
            const long row = mBase + wm + i * 16 + q * 4 + r;
            const long rowOff = row * (long)N;
#pragma unroll
            for (int j = 0; j < 4; ++j) {
                const long idx = rowOff + colBase + j * 16;
                const float val = acc[i][j][r];
                if (EPI == 0) {
                    ((u16*)outp)[idx] = f2bf(val);
                } else if (EPI == 1) {
                    ((float*)outp)[idx] = ((const float*)aux1)[idx] + val;
                } else if (EPI == 2) {
                    const float t = val > 0.f ? val * val : 0.f;
                    ((u16*)outp)[idx] = f2bf(t);
                } else if (EPI == 3) {
                    const float sg = __fdividef(1.f, 1.f + __expf(-val));
                    ((u16*)outp)[idx] = f2bf(sg);
                } else {
                    const float t = ((const float*)aux1)[idx]
                                  + bf2f(((const u16*)aux2)[idx]) * val;
                    ((float*)outp)[idx] = t;
                }
            }
        }
    }
}

// ---------------------------------------------------------------------------
// Bidirectional WKV scan: grid (16, B, 2); one wave per 64 channels/batch/dir.
// 4-deep k/v prefetch to hide load latency behind the serial exp chain.
// ---------------------------------------------------------------------------
__global__ __launch_bounds__(64)
void wkv_scan(const u16* __restrict__ kbuf, const u16* __restrict__ vbuf,
              const float* __restrict__ decay, const float* __restrict__ uarr,
              u16* __restrict__ wkvf, u16* __restrict__ wkvb)
{
    const int c = blockIdx.x * 64 + threadIdx.x;
    const int dir = blockIdx.z;
    const long bb = (long)blockIdx.y * (1024 * 1024) + c;
    const long stride = dir ? -1024 : 1024;
    long idx = dir ? bb + 1023 * 1024 : bb;
    u16* __restrict__ dst = dir ? wkvb : wkvf;

    const float w  = -__expf(decay[c]);
    const float uu = uarr[c];
    float a = 0.f, b = 0.f, p = -1e38f;

    float kq[4], vq[4];
#pragma unroll
    for (int j = 0; j < 4; ++j) {
        kq[j] = bf2f(kbuf[idx + j * stride]);
        vq[j] = bf2f(vbuf[idx + j * stride]);
    }
    for (int tb = 0; tb < 256; ++tb) {
        float kn[4], vn[4];
        if (tb < 255) {
#pragma unroll
            for (int j = 0; j < 4; ++j) {
                kn[j] = bf2f(kbuf[idx + (j + 4) * stride]);
                vn[j] = bf2f(vbuf[idx + (j + 4) * stride]);
            }
        }
#pragma unroll
        for (int j = 0; j < 4; ++j) {
            const float kk = kq[j], vv = vq[j];
            const float q1 = fmaxf(p, uu + kk);
            const float e1 = __expf(p - q1);
            const float e2 = __expf(uu + kk - q1);
            dst[idx + j * stride] = f2bf(__fdividef(e1 * a + e2 * vv, e1 * b + e2));
            const float q2 = fmaxf(p + w, kk);
            const float f1 = __expf(p + w - q2);
            const float f2 = __expf(kk - q2);
            a = f1 * a + f2 * vv;
            b = f1 * b + f2;
            p = q2;
        }
#pragma unroll
        for (int j = 0; j < 4; ++j) { kq[j] = kn[j]; vq[j] = vn[j]; }
        idx += 4 * stride;
    }
}

// ---------------------------------------------------------------------------
// combine: rwkv = sigmoid(r_pre) * 0.5 * (wkv_f + wkv_b); in-place over wkv_f
// ---------------------------------------------------------------------------
__global__ __launch_bounds__(256)
void combine_kernel(u16* __restrict__ wkvf, const u16* __restrict__ wkvb,
                    const u16* __restrict__ rpre)
{
    const int i = blockIdx.x * 256 + threadIdx.x;
    ushort4 fv = ((const ushort4*)wkvf)[i];
    ushort4 bv = ((const ushort4*)wkvb)[i];
    ushort4 rv = ((const ushort4*)rpre)[i];
    ushort4 o;
    {
        float r0 = __fdividef(1.f, 1.f + __expf(-bf2f(rv.x)));
        float r1 = __fdividef(1.f, 1.f + __expf(-bf2f(rv.y)));
        float r2 = __fdividef(1.f, 1.f + __expf(-bf2f(rv.z)));
        float r3 = __fdividef(1.f, 1.f + __expf(-bf2f(rv.w)));
        o.x = f2bf(r0 * 0.5f * (bf2f(fv.x) + bf2f(bv.x)));
        o.y = f2bf(r1 * 0.5f * (bf2f(fv.y) + bf2f(bv.y)));
        o.z = f2bf(r2 * 0.5f * (bf2f(fv.z) + bf2f(bv.z)));
        o.w = f2bf(r3 * 0.5f * (bf2f(fv.w) + bf2f(bv.w)));
    }
    ((ushort4*)wkvf)[i] = o;
}

// ---------------------------------------------------------------------------
extern "C" void kernel_launch(void* const* d_in, const int* in_sizes, int n_in,
                              void* d_out, int out_size, void* d_ws, size_t ws_size,
                              hipStream_t stream)
{
    (void)in_sizes; (void)n_in; (void)out_size; (void)ws_size;
    const float* x     = (const float*)d_in[0];
    const float* ln1w  = (const float*)d_in[1];
    const float* ln1b  = (const float*)d_in[2];
    const float* ln2w  = (const float*)d_in[3];
    const float* ln2b  = (const float*)d_in[4];
    const float* Wr    = (const float*)d_in[5];
    const float* Wk    = (const float*)d_in[6];
    const float* Wv    = (const float*)d_in[7];
    const float* Wo    = (const float*)d_in[8];
    const float* decay = (const float*)d_in[9];
    const float* uarr  = (const float*)d_in[10];
    const float* Wfk   = (const float*)d_in[11];
    const float* Wfv   = (const float*)d_in[12];
    const float* Wfr   = (const float*)d_in[13];

    const int M = 8192, C = 1024, C4 = 4096;
    const size_t MB = 1024u * 1024u;
    char* ws = (char*)d_ws;
    // workspace layout (154 MB total)
    float* X2   = (float*)(ws);              // [0,32)    x after time-mix (fp32)
    u16*  XN    = (u16*)(ws + 32 * MB);      // [32,48)   xn / xn2
    u16*  RP    = (u16*)(ws + 48 * MB);      // [48,64)   r_pre, later ffn sigmoid
    u16*  KB    = (u16*)(ws + 64 * MB);      // [64,80)   k
    u16*  VB    = (u16*)(ws + 80 * MB);      // [80,96)   v
    u16*  WKVF  = (u16*)(ws + 96 * MB);      // [96,112)  fwd wkv -> rwkv (combine in-place)
    u16*  WKVB  = (u16*)(ws + 112 * MB);     // [112,128) bwd wkv
    u16*  KK    = (u16*)(ws + 64 * MB);      // [64,128)  ffn relu^2 key (reuse)
    u16*  WrB   = (u16*)(ws + 128 * MB);     // bf16 weight copies
    u16*  WkB   = (u16*)(ws + 130 * MB);
    u16*  WvB   = (u16*)(ws + 132 * MB);
    u16*  WoB   = (u16*)(ws + 134 * MB);
    u16*  WfrB  = (u16*)(ws + 136 * MB);
    u16*  WfkB  = (u16*)(ws + 138 * MB);     // 8 MB
    u16*  WfvB  = (u16*)(ws + 146 * MB);     // 8 MB -> ends 154 MB

    const dim3 blk(256);
    const dim3 gC(C / 128, M / 128);
    const dim3 gC4(C4 / 128, M / 128);
    const int n4_1M = C * C / 4, n4_4M = C * C4 / 4;

    f2bf_kernel<<<dim3(n4_1M / 256), blk, 0, stream>>>(Wr,  WrB,  n4_1M);
    f2bf_kernel<<<dim3(n4_1M / 256), blk, 0, stream>>>(Wk,  WkB,  n4_1M);
    f2bf_kernel<<<dim3(n4_1M / 256), blk, 0, stream>>>(Wv,  WvB,  n4_1M);
    f2bf_kernel<<<dim3(n4_1M / 256), blk, 0, stream>>>(Wo,  WoB,  n4_1M);
    f2bf_kernel<<<dim3(n4_1M / 256), blk, 0, stream>>>(Wfr, WfrB, n4_1M);
    f2bf_kernel<<<dim3(n4_4M / 256), blk, 0, stream>>>(Wfk, WfkB, n4_4M);
    f2bf_kernel<<<dim3(n4_4M / 256), blk, 0, stream>>>(Wfv, WfvB, n4_4M);

    ln_kernel<<<dim3(M), blk, 0, stream>>>(x, ln1w, ln1b, XN);
    gemm_bt<0><<<gC, blk, 0, stream>>>(XN, WrB, M, C, C, RP, nullptr, nullptr);
    gemm_bt<0><<<gC, blk, 0, stream>>>(XN, WkB, M, C, C, KB, nullptr, nullptr);
    gemm_bt<0><<<gC, blk, 0, stream>>>(XN, WvB, M, C, C, VB, nullptr, nullptr);
    wkv_scan<<<dim3(16, 8, 2), dim3(64), 0, stream>>>(KB, VB, decay, uarr, WKVF, WKVB);
    combine_kernel<<<dim3(M * C / 4 / 256), blk, 0, stream>>>(WKVF, WKVB, RP);
    gemm_bt<1><<<gC, blk, 0, stream>>>(WKVF, WoB, M, C, C, X2, x, nullptr);
    ln_kernel<<<dim3(M), blk, 0, stream>>>(X2, ln2w, ln2b, XN);
    gemm_bt<2><<<gC4, blk, 0, stream>>>(XN, WfkB, M, C4, C, KK, nullptr, nullptr);
    gemm_bt<3><<<gC, blk, 0, stream>>>(XN, WfrB, M, C, C, RP, nullptr, nullptr);
    gemm_bt<4><<<gC, blk, 0, stream>>>(KK, WfvB, M, C, C4, d_out, X2, RP);
}

// Round 3
// 561.396 us; speedup vs baseline: 1.1613x; 1.1613x over previous
//
#include <hip/hip_runtime.h>
#include <cstdint>
#include <cstddef>

typedef unsigned short u16;
typedef __bf16 bf16_t;
typedef bf16_t bf16x8 __attribute__((ext_vector_type(8)));
typedef float f32x4 __attribute__((ext_vector_type(4)));

#define GCH 16          // scan chunks
#define TCH 64          // steps per chunk (1024 / GCH)

static __device__ __forceinline__ float bf2f(u16 v) {
    union { unsigned int u; float f; } cv;
    cv.u = ((unsigned int)v) << 16;
    return cv.f;
}
static __device__ __forceinline__ u16 f2bf(float f) {
    union { float f; unsigned int u; } cv;
    cv.f = f;
    unsigned int r = 0x7fffu + ((cv.u >> 16) & 1u);
    return (u16)((cv.u + r) >> 16);
}

// ---------------------------------------------------------------------------
// fp32 -> bf16 conversion (weights), 4 elems/thread
// ---------------------------------------------------------------------------
__global__ __launch_bounds__(256)
void f2bf_kernel(const float* __restrict__ in, u16* __restrict__ out, int n4)
{
    const int i = blockIdx.x * 256 + threadIdx.x;
    if (i < n4) {
        float4 f = ((const float4*)in)[i];
        ushort4 o;
        o.x = f2bf(f.x); o.y = f2bf(f.y); o.z = f2bf(f.z); o.w = f2bf(f.w);
        ((ushort4*)out)[i] = o;
    }
}

// ---------------------------------------------------------------------------
// LayerNorm over rows of 1024, fp32 in, bf16 out. 256 thr/row.
// ---------------------------------------------------------------------------
__global__ __launch_bounds__(256)
void ln_kernel(const float* __restrict__ xin, const float* __restrict__ w,
               const float* __restrict__ b, u16* __restrict__ out)
{
    const int row = blockIdx.x;
    const int tid = threadIdx.x;
    const float4 f = ((const float4*)(xin + (size_t)row * 1024))[tid];
    float vals[4] = { f.x, f.y, f.z, f.w };
    float s  = vals[0] + vals[1] + vals[2] + vals[3];
    float ss = vals[0]*vals[0] + vals[1]*vals[1] + vals[2]*vals[2] + vals[3]*vals[3];
    for (int off = 32; off; off >>= 1) {
        s  += __shfl_down(s, off, 64);
        ss += __shfl_down(ss, off, 64);
    }
    __shared__ float redS[4], redQ[4];
    if ((tid & 63) == 0) { redS[tid >> 6] = s; redQ[tid >> 6] = ss; }
    __syncthreads();
    s  = redS[0] + redS[1] + redS[2] + redS[3];
    ss = redQ[0] + redQ[1] + redQ[2] + redQ[3];
    const float mu  = s * (1.f / 1024.f);
    const float var = ss * (1.f / 1024.f) - mu * mu;
    const float rs  = rsqrtf(var + 1e-5f);
    const float4 wv = ((const float4*)w)[tid];
    const float4 bv = ((const float4*)b)[tid];
    ushort4 o;
    o.x = f2bf((vals[0] - mu) * rs * wv.x + bv.x);
    o.y = f2bf((vals[1] - mu) * rs * wv.y + bv.y);
    o.z = f2bf((vals[2] - mu) * rs * wv.z + bv.z);
    o.w = f2bf((vals[3] - mu) * rs * wv.w + bv.w);
    ((ushort4*)(out + (size_t)row * 1024))[tid] = o;
}

// ---------------------------------------------------------------------------
// GEMM: out[M,N] = A[M,K] @ B[N,K]^T  (bf16 in, K contiguous), m97 recipe.
// EPI: 0: bf16(acc); 1: f32(aux1)+acc -> f32; 2: bf16(relu(acc)^2);
//      3: bf16(sigmoid(acc)); 4: f32(aux1)+bf16(aux2)*acc -> f32
// ---------------------------------------------------------------------------
template<int EPI>
__global__ __launch_bounds__(256)
void gemm_bt(const u16* __restrict__ A, const u16* __restrict__ B,
             int M, int N, int K,
             void* __restrict__ outp,
             const void* __restrict__ aux1, const void* __restrict__ aux2)
{
    __shared__ u16 lA[128 * 64];
    __shared__ u16 lB[128 * 64];
    const int tid  = threadIdx.x;
    const int wave = tid >> 6;
    const int lane = tid & 63;
    const int q    = lane >> 4;
    const int l16  = lane & 15;
    const long mBase = (long)blockIdx.y * 128;
    const long nBase = (long)blockIdx.x * 128;
    const int wm = (wave >> 1) * 64;
    const int wn = (wave & 1) * 64;

    f32x4 acc[4][4];
#pragma unroll
    for (int i = 0; i < 4; ++i)
#pragma unroll
        for (int j = 0; j < 4; ++j)
#pragma unroll
            for (int r = 0; r < 4; ++r) acc[i][j][r] = 0.f;

    const int srow = tid >> 3;
    const int scol = (tid & 7) * 8;
    const int ldsW = wave * 512;

    for (int kb = 0; kb < K; kb += 64) {
        __syncthreads();
#pragma unroll
        for (int c = 0; c < 4; ++c) {
            const int row = c * 32 + srow;
            const u16* ga = A + (mBase + row) * (long)K + kb + scol;
            const u16* gb = B + (nBase + row) * (long)K + kb + scol;
            __builtin_amdgcn_global_load_lds(
                (const __attribute__((address_space(1))) void*)ga,
                (__attribute__((address_space(3))) void*)(lA + c * 2048 + ldsW),
                16, 0, 0);
            __builtin_amdgcn_global_load_lds(
                (const __attribute__((address_space(1))) void*)gb,
                (__attribute__((address_space(3))) void*)(lB + c * 2048 + ldsW),
                16, 0, 0);
        }
        __syncthreads();
#pragma unroll
        for (int ks = 0; ks < 2; ++ks) {
            bf16x8 af[4], bfm[4];
#pragma unroll
            for (int i = 0; i < 4; ++i) {
                af[i]  = *(const bf16x8*)(lA + (wm + i * 16 + l16) * 64 + ks * 32 + q * 8);
                bfm[i] = *(const bf16x8*)(lB + (wn + i * 16 + l16) * 64 + ks * 32 + q * 8);
            }
#pragma unroll
            for (int i = 0; i < 4; ++i)
#pragma unroll
                for (int j = 0; j < 4; ++j)
                    acc[i][j] = __builtin_amdgcn_mfma_f32_16x16x32_bf16(
                        af[i], bfm[j], acc[i][j], 0, 0, 0);
        }
    }

    const long colBase = nBase + wn + l16;
#pragma unroll
    for (int i = 0; i < 4; ++i) {
#pragma unroll
        for (int r = 0; r < 4; ++r) {
            const long row = mBase + wm + i * 16 + q * 4 + r;
            const long rowOff = row * (long)N;
#pragma unroll
            for (int j = 0; j < 4; ++j) {
                const long idx = rowOff + colBase + j * 16;
                const float val = acc[i][j][r];
                if (EPI == 0) {
                    ((u16*)outp)[idx] = f2bf(val);
                } else if (EPI == 1) {
                    ((float*)outp)[idx] = ((const float*)aux1)[idx] + val;
                } else if (EPI == 2) {
                    const float t = val > 0.f ? val * val : 0.f;
                    ((u16*)outp)[idx] = f2bf(t);
                } else if (EPI == 3) {
                    const float sg = __fdividef(1.f, 1.f + __expf(-val));
                    ((u16*)outp)[idx] = f2bf(sg);
                } else {
                    const float t = ((const float*)aux1)[idx]
                                  + bf2f(((const u16*)aux2)[idx]) * val;
                    ((float*)outp)[idx] = t;
                }
            }
        }
    }
}

// ---------------------------------------------------------------------------
// Chunked WKV scan. State (a,b,p) with true A=a*e^p, B=b*e^p is associative:
//   fold prior over L steps: pd=p1+w*L; q=max(pd,p2);
//   a=e^(pd-q)*a1+e^(p2-q)*a2; b likewise; p=q.
// Phase 1 (wkv_sum): per-chunk local summary. Phase 2 (wkv_out): fold
// preceding summaries, then emit outputs for own chunk.
// grid (16, B, 2*GCH): z&1 = dir, z>>1 = chunk. One wave / 64 channels.
// ---------------------------------------------------------------------------
__global__ __launch_bounds__(64)
void wkv_sum(const u16* __restrict__ kbuf, const u16* __restrict__ vbuf,
             const float* __restrict__ decay,
             float* __restrict__ sumA, float* __restrict__ sumB,
             float* __restrict__ sumP)
{
    const int c   = blockIdx.x * 64 + threadIdx.x;
    const int bt  = blockIdx.y;
    const int dir = blockIdx.z & 1;
    const int g   = blockIdx.z >> 1;
    const long base = (long)bt * (1024 * 1024) + c;
    const long stride = dir ? -1024 : 1024;
    long idx = dir ? base + (long)(1023 - g * TCH) * 1024
                   : base + (long)(g * TCH) * 1024;
    const float w = -__expf(decay[c]);
    float a = 0.f, b = 0.f, p = -1e38f;

    float kq[8], vq[8];
#pragma unroll
    for (int j = 0; j < 8; ++j) {
        kq[j] = bf2f(kbuf[idx + j * stride]);
        vq[j] = bf2f(vbuf[idx + j * stride]);
    }
    for (int tb = 0; tb < TCH / 8; ++tb) {
        float kn[8], vn[8];
        if (tb < TCH / 8 - 1) {
#pragma unroll
            for (int j = 0; j < 8; ++j) {
                kn[j] = bf2f(kbuf[idx + (j + 8) * stride]);
                vn[j] = bf2f(vbuf[idx + (j + 8) * stride]);
            }
        }
#pragma unroll
        for (int j = 0; j < 8; ++j) {
            const float kk = kq[j], vv = vq[j];
            const float pw = p + w;
            const float q2 = fmaxf(pw, kk);
            const float f1 = __expf(pw - q2);
            const float f2 = __expf(kk - q2);
            a = f1 * a + f2 * vv;
            b = f1 * b + f2;
            p = q2;
        }
#pragma unroll
        for (int j = 0; j < 8; ++j) { kq[j] = kn[j]; vq[j] = vn[j]; }
        idx += 8 * stride;
    }
    const int sidx = (((dir * GCH + g) * 8 + bt) << 10) + c;
    sumA[sidx] = a; sumB[sidx] = b; sumP[sidx] = p;
}

__global__ __launch_bounds__(64)
void wkv_out(const u16* __restrict__ kbuf, const u16* __restrict__ vbuf,
             const float* __restrict__ decay, const float* __restrict__ uarr,
             const float* __restrict__ sumA, const float* __restrict__ sumB,
             const float* __restrict__ sumP,
             u16* __restrict__ wkvf, u16* __restrict__ wkvb)
{
    const int c   = blockIdx.x * 64 + threadIdx.x;
    const int bt  = blockIdx.y;
    const int dir = blockIdx.z & 1;
    const int g   = blockIdx.z >> 1;
    const long base = (long)bt * (1024 * 1024) + c;
    const long stride = dir ? -1024 : 1024;
    long idx = dir ? base + (long)(1023 - g * TCH) * 1024
                   : base + (long)(g * TCH) * 1024;
    u16* __restrict__ dst = dir ? wkvb : wkvf;

    const float w  = -__expf(decay[c]);
    const float uu = uarr[c];
    float a = 0.f, b = 0.f, p = -1e38f;
    // fold summaries of preceding chunks (scan direction order)
    for (int gg = 0; gg < g; ++gg) {
        const int sidx = (((dir * GCH + gg) * 8 + bt) << 10) + c;
        const float a2 = sumA[sidx], b2 = sumB[sidx], p2 = sumP[sidx];
        const float pd = p + w * (float)TCH;
        const float qq = fmaxf(pd, p2);
        const float x1 = __expf(pd - qq);
        const float x2 = __expf(p2 - qq);
        a = x1 * a + x2 * a2;
        b = x1 * b + x2 * b2;
        p = qq;
    }

    float kq[8], vq[8];
#pragma unroll
    for (int j = 0; j < 8; ++j) {
        kq[j] = bf2f(kbuf[idx + j * stride]);
        vq[j] = bf2f(vbuf[idx + j * stride]);
    }
    for (int tb = 0; tb < TCH / 8; ++tb) {
        float kn[8], vn[8];
        if (tb < TCH / 8 - 1) {
#pragma unroll
            for (int j = 0; j < 8; ++j) {
                kn[j] = bf2f(kbuf[idx + (j + 8) * stride]);
                vn[j] = bf2f(vbuf[idx + (j + 8) * stride]);
            }
        }
#pragma unroll
        for (int j = 0; j < 8; ++j) {
            const float kk = kq[j], vv = vq[j];
            const float uk = uu + kk;
            const float q1 = fmaxf(p, uk);
            const float e1 = __expf(p - q1);
            const float e2 = __expf(uk - q1);
            dst[idx + j * stride] = f2bf(__fdividef(e1 * a + e2 * vv, e1 * b + e2));
            const float pw = p + w;
            const float q2 = fmaxf(pw, kk);
            const float f1 = __expf(pw - q2);
            const float f2 = __expf(kk - q2);
            a = f1 * a + f2 * vv;
            b = f1 * b + f2;
            p = q2;
        }
#pragma unroll
        for (int j = 0; j < 8; ++j) { kq[j] = kn[j]; vq[j] = vn[j]; }
        idx += 8 * stride;
    }
}

// ---------------------------------------------------------------------------
// combine: rwkv = sigmoid(r_pre) * 0.5 * (wkv_f + wkv_b); in-place over wkv_f
// ---------------------------------------------------------------------------
__global__ __launch_bounds__(256)
void combine_kernel(u16* __restrict__ wkvf, const u16* __restrict__ wkvb,
                    const u16* __restrict__ rpre)
{
    const int i = blockIdx.x * 256 + threadIdx.x;
    ushort4 fv = ((const ushort4*)wkvf)[i];
    ushort4 bv = ((const ushort4*)wkvb)[i];
    ushort4 rv = ((const ushort4*)rpre)[i];
    ushort4 o;
    {
        float r0 = __fdividef(1.f, 1.f + __expf(-bf2f(rv.x)));
        float r1 = __fdividef(1.f, 1.f + __expf(-bf2f(rv.y)));
        float r2 = __fdividef(1.f, 1.f + __expf(-bf2f(rv.z)));
        float r3 = __fdividef(1.f, 1.f + __expf(-bf2f(rv.w)));
        o.x = f2bf(r0 * 0.5f * (bf2f(fv.x) + bf2f(bv.x)));
        o.y = f2bf(r1 * 0.5f * (bf2f(fv.y) + bf2f(bv.y)));
        o.z = f2bf(r2 * 0.5f * (bf2f(fv.z) + bf2f(bv.z)));
        o.w = f2bf(r3 * 0.5f * (bf2f(fv.w) + bf2f(bv.w)));
    }
    ((ushort4*)wkvf)[i] = o;
}

// ---------------------------------------------------------------------------
extern "C" void kernel_launch(void* const* d_in, const int* in_sizes, int n_in,
                              void* d_out, int out_size, void* d_ws, size_t ws_size,
                              hipStream_t stream)
{
    (void)in_sizes; (void)n_in; (void)out_size; (void)ws_size;
    const float* x     = (const float*)d_in[0];
    const float* ln1w  = (const float*)d_in[1];
    const float* ln1b  = (const float*)d_in[2];
    const float* ln2w  = (const float*)d_in[3];
    const float* ln2b  = (const float*)d_in[4];
    const float* Wr    = (const float*)d_in[5];
    const float* Wk    = (const float*)d_in[6];
    const float* Wv    = (const float*)d_in[7];
    const float* Wo    = (const float*)d_in[8];
    const float* decay = (const float*)d_in[9];
    const float* uarr  = (const float*)d_in[10];
    const float* Wfk   = (const float*)d_in[11];
    const float* Wfv   = (const float*)d_in[12];
    const float* Wfr   = (const float*)d_in[13];

    const int M = 8192, C = 1024, C4 = 4096;
    const size_t MB = 1024u * 1024u;
    char* ws = (char*)d_ws;
    // workspace layout (154 MB total)
    float* X2   = (float*)(ws);              // [0,32)    x after time-mix (fp32)
    u16*  XN    = (u16*)(ws + 32 * MB);      // [32,48)   xn / xn2
    u16*  RP    = (u16*)(ws + 48 * MB);      // [48,64)   r_pre, later ffn sigmoid
    u16*  KB    = (u16*)(ws + 64 * MB);      // [64,80)   k
    u16*  VB    = (u16*)(ws + 80 * MB);      // [80,96)   v
    u16*  WKVF  = (u16*)(ws + 96 * MB);      // [96,112)  fwd wkv -> rwkv (in-place)
    u16*  WKVB  = (u16*)(ws + 112 * MB);     // [112,128) bwd wkv
    u16*  KK    = (u16*)(ws + 64 * MB);      // [64,128)  ffn relu^2 key (reuse)
    u16*  WrB   = (u16*)(ws + 128 * MB);     // bf16 weight copies
    u16*  WkB   = (u16*)(ws + 130 * MB);
    u16*  WvB   = (u16*)(ws + 132 * MB);
    u16*  WoB   = (u16*)(ws + 134 * MB);
    u16*  WfrB  = (u16*)(ws + 136 * MB);
    u16*  WfkB  = (u16*)(ws + 138 * MB);     // 8 MB
    u16*  WfvB  = (u16*)(ws + 146 * MB);     // 8 MB -> ends 154 MB
    // scan summaries live in the X2 region (free until gemm_bt<1> writes it)
    float* sumA = (float*)(ws);              // 2*GCH*8*1024 floats = 1 MB
    float* sumB = (float*)(ws + 4 * MB);
    float* sumP = (float*)(ws + 8 * MB);

    const dim3 blk(256);
    const dim3 gC(C / 128, M / 128);
    const dim3 gC4(C4 / 128, M / 128);
    const int n4_1M = C * C / 4, n4_4M = C * C4 / 4;

    f2bf_kernel<<<dim3(n4_1M / 256), blk, 0, stream>>>(Wr,  WrB,  n4_1M);
    f2bf_kernel<<<dim3(n4_1M / 256), blk, 0, stream>>>(Wk,  WkB,  n4_1M);
    f2bf_kernel<<<dim3(n4_1M / 256), blk, 0, stream>>>(Wv,  WvB,  n4_1M);
    f2bf_kernel<<<dim3(n4_1M / 256), blk, 0, stream>>>(Wo,  WoB,  n4_1M);
    f2bf_kernel<<<dim3(n4_1M / 256), blk, 0, stream>>>(Wfr, WfrB, n4_1M);
    f2bf_kernel<<<dim3(n4_4M / 256), blk, 0, stream>>>(Wfk, WfkB, n4_4M);
    f2bf_kernel<<<dim3(n4_4M / 256), blk, 0, stream>>>(Wfv, WfvB, n4_4M);

    ln_kernel<<<dim3(M), blk, 0, stream>>>(x, ln1w, ln1b, XN);
    gemm_bt<0><<<gC, blk, 0, stream>>>(XN, WrB, M, C, C, RP, nullptr, nullptr);
    gemm_bt<0><<<gC, blk, 0, stream>>>(XN, WkB, M, C, C, KB, nullptr, nullptr);
    gemm_bt<0><<<gC, blk, 0, stream>>>(XN, WvB, M, C, C, VB, nullptr, nullptr);
    wkv_sum<<<dim3(16, 8, 2 * GCH), dim3(64), 0, stream>>>(KB, VB, decay,
                                                           sumA, sumB, sumP);
    wkv_out<<<dim3(16, 8, 2 * GCH), dim3(64), 0, stream>>>(KB, VB, decay, uarr,
                                                           sumA, sumB, sumP,
                                                           WKVF, WKVB);
    combine_kernel<<<dim3(M * C / 4 / 256), blk, 0, stream>>>(WKVF, WKVB, RP);
    gemm_bt<1><<<gC, blk, 0, stream>>>(WKVF, WoB, M, C, C, X2, x, nullptr);
    ln_kernel<<<dim3(M), blk, 0, stream>>>(X2, ln2w, ln2b, XN);
    gemm_bt<2><<<gC4, blk, 0, stream>>>(XN, WfkB, M, C4, C, KK, nullptr, nullptr);
    gemm_bt<3><<<gC, blk, 0, stream>>>(XN, WfrB, M, C, C, RP, nullptr, nullptr);
    gemm_bt<4><<<gC, blk, 0, stream>>>(KK, WfvB, M, C, C4, d_out, X2, RP);
}

// Round 4
// 535.036 us; speedup vs baseline: 1.2185x; 1.0493x over previous
//
#include <hip/hip_runtime.h>
#include <cstdint>
#include <cstddef>

typedef unsigned short u16;
typedef __bf16 bf16_t;
typedef bf16_t bf16x8 __attribute__((ext_vector_type(8)));
typedef float f32x4 __attribute__((ext_vector_type(4)));

#define GCH 16          // scan chunks
#define TCH 64          // steps per chunk (1024 / GCH)

static __device__ __forceinline__ float bf2f(u16 v) {
    union { unsigned int u; float f; } cv;
    cv.u = ((unsigned int)v) << 16;
    return cv.f;
}
static __device__ __forceinline__ u16 f2bf(float f) {
    union { float f; unsigned int u; } cv;
    cv.f = f;
    unsigned int r = 0x7fffu + ((cv.u >> 16) & 1u);
    return (u16)((cv.u + r) >> 16);
}

// ---------------------------------------------------------------------------
// fp32 -> bf16 conversion (weights), 4 elems/thread
// ---------------------------------------------------------------------------
__global__ __launch_bounds__(256)
void f2bf_kernel(const float* __restrict__ in, u16* __restrict__ out, int n4)
{
    const int i = blockIdx.x * 256 + threadIdx.x;
    if (i < n4) {
        float4 f = ((const float4*)in)[i];
        ushort4 o;
        o.x = f2bf(f.x); o.y = f2bf(f.y); o.z = f2bf(f.z); o.w = f2bf(f.w);
        ((ushort4*)out)[i] = o;
    }
}

// ---------------------------------------------------------------------------
// LayerNorm over rows of 1024, fp32 in, bf16 out. 256 thr/row.
// ---------------------------------------------------------------------------
__global__ __launch_bounds__(256)
void ln_kernel(const float* __restrict__ xin, const float* __restrict__ w,
               const float* __restrict__ b, u16* __restrict__ out)
{
    const int row = blockIdx.x;
    const int tid = threadIdx.x;
    const float4 f = ((const float4*)(xin + (size_t)row * 1024))[tid];
    float vals[4] = { f.x, f.y, f.z, f.w };
    float s  = vals[0] + vals[1] + vals[2] + vals[3];
    float ss = vals[0]*vals[0] + vals[1]*vals[1] + vals[2]*vals[2] + vals[3]*vals[3];
    for (int off = 32; off; off >>= 1) {
        s  += __shfl_down(s, off, 64);
        ss += __shfl_down(ss, off, 64);
    }
    __shared__ float redS[4], redQ[4];
    if ((tid & 63) == 0) { redS[tid >> 6] = s; redQ[tid >> 6] = ss; }
    __syncthreads();
    s  = redS[0] + redS[1] + redS[2] + redS[3];
    ss = redQ[0] + redQ[1] + redQ[2] + redQ[3];
    const float mu  = s * (1.f / 1024.f);
    const float var = ss * (1.f / 1024.f) - mu * mu;
    const float rs  = rsqrtf(var + 1e-5f);
    const float4 wv = ((const float4*)w)[tid];
    const float4 bv = ((const float4*)b)[tid];
    ushort4 o;
    o.x = f2bf((vals[0] - mu) * rs * wv.x + bv.x);
    o.y = f2bf((vals[1] - mu) * rs * wv.y + bv.y);
    o.z = f2bf((vals[2] - mu) * rs * wv.z + bv.z);
    o.w = f2bf((vals[3] - mu) * rs * wv.w + bv.w);
    ((ushort4*)(out + (size_t)row * 1024))[tid] = o;
}

// ---------------------------------------------------------------------------
// GEMM: out[M,N] = A[M,K] @ B[N,K]^T  (bf16 in, K contiguous), m97 recipe
// + XOR bank-conflict swizzle: LDS[row][g] holds global[row][g ^ (row&7)]
//   (column groups of 8 bf16 = 16 B). global_load_lds dest is lane-fixed, so
//   the swizzle is applied on the *global* address at staging and undone at
//   fragment read: group' = (ks*4+q) ^ (l16&7). Kills the 8-way conflict
//   from the 128 B row stride (all rows alias to the same banks).
// EPI: 0: bf16(acc); 1: f32(aux1)+acc -> f32; 2: bf16(relu(acc)^2);
//      3: bf16(sigmoid(acc)); 4: f32(aux1)+bf16(aux2)*acc -> f32
// ---------------------------------------------------------------------------
template<int EPI>
__global__ __launch_bounds__(256)
void gemm_bt(const u16* __restrict__ A, const u16* __restrict__ B,
             int M, int N, int K,
             void* __restrict__ outp,
             const void* __restrict__ aux1, const void* __restrict__ aux2)
{
    __shared__ u16 lA[128 * 64];
    __shared__ u16 lB[128 * 64];
    const int tid  = threadIdx.x;
    const int wave = tid >> 6;
    const int lane = tid & 63;
    const int q    = lane >> 4;
    const int l16  = lane & 15;
    const long mBase = (long)blockIdx.y * 128;
    const long nBase = (long)blockIdx.x * 128;
    const int wm = (wave >> 1) * 64;
    const int wn = (wave & 1) * 64;

    f32x4 acc[4][4];
#pragma unroll
    for (int i = 0; i < 4; ++i)
#pragma unroll
        for (int j = 0; j < 4; ++j)
#pragma unroll
            for (int r = 0; r < 4; ++r) acc[i][j][r] = 0.f;

    // staging: lane (tid) in chunk c lands at LDS row c*32+(tid>>3),
    // col group tid&7; it loads the swizzled global col group.
    const int srow = tid >> 3;
    const int scol = ((tid & 7) ^ (srow & 7)) * 8;
    const int ldsW = wave * 512;
    // fragment-read swizzle groups (per lane, constant over K loop)
    const int swz = l16 & 7;

    for (int kb = 0; kb < K; kb += 64) {
        __syncthreads();
#pragma unroll
        for (int c = 0; c < 4; ++c) {
            const int row = c * 32 + srow;
            const u16* ga = A + (mBase + row) * (long)K + kb + scol;
            const u16* gb = B + (nBase + row) * (long)K + kb + scol;
            __builtin_amdgcn_global_load_lds(
                (const __attribute__((address_space(1))) void*)ga,
                (__attribute__((address_space(3))) void*)(lA + c * 2048 + ldsW),
                16, 0, 0);
            __builtin_amdgcn_global_load_lds(
                (const __attribute__((address_space(1))) void*)gb,
                (__attribute__((address_space(3))) void*)(lB + c * 2048 + ldsW),
                16, 0, 0);
        }
        __syncthreads();
#pragma unroll
        for (int ks = 0; ks < 2; ++ks) {
            const int grp = ((ks * 4 + q) ^ swz) * 8;
            bf16x8 af[4], bfm[4];
#pragma unroll
            for (int i = 0; i < 4; ++i) {
                af[i]  = *(const bf16x8*)(lA + (wm + i * 16 + l16) * 64 + grp);
                bfm[i] = *(const bf16x8*)(lB + (wn + i * 16 + l16) * 64 + grp);
            }
#pragma unroll
            for (int i = 0; i < 4; ++i)
#pragma unroll
                for (int j = 0; j < 4; ++j)
                    acc[i][j] = __builtin_amdgcn_mfma_f32_16x16x32_bf16(
                        af[i], bfm[j], acc[i][j], 0, 0, 0);
        }
    }

    const long colBase = nBase + wn + l16;
#pragma unroll
    for (int i = 0; i < 4; ++i) {
#pragma unroll
        for (int r = 0; r < 4; ++r) {
            const long row = mBase + wm + i * 16 + q * 4 + r;
            const long rowOff = row * (long)N;
#pragma unroll
            for (int j = 0; j < 4; ++j) {
                const long idx = rowOff + colBase + j * 16;
                const float val = acc[i][j][r];
                if (EPI == 0) {
                    ((u16*)outp)[idx] = f2bf(val);
                } else if (EPI == 1) {
                    ((float*)outp)[idx] = ((const float*)aux1)[idx] + val;
                } else if (EPI == 2) {
                    const float t = val > 0.f ? val * val : 0.f;
                    ((u16*)outp)[idx] = f2bf(t);
                } else if (EPI == 3) {
                    const float sg = __fdividef(1.f, 1.f + __expf(-val));
                    ((u16*)outp)[idx] = f2bf(sg);
                } else {
                    const float t = ((const float*)aux1)[idx]
                                  + bf2f(((const u16*)aux2)[idx]) * val;
                    ((float*)outp)[idx] = t;
                }
            }
        }
    }
}

// ---------------------------------------------------------------------------
// Chunked WKV scan (associative (a,b,p) monoid). Phase 1: per-chunk summary.
// Phase 2: fold preceding summaries, emit own chunk's outputs.
// grid (16, B, 2*GCH): z&1 = dir, z>>1 = chunk. One wave / 64 channels.
// ---------------------------------------------------------------------------
__global__ __launch_bounds__(64)
void wkv_sum(const u16* __restrict__ kbuf, const u16* __restrict__ vbuf,
             const float* __restrict__ decay,
             float* __restrict__ sumA, float* __restrict__ sumB,
             float* __restrict__ sumP)
{
    const int c   = blockIdx.x * 64 + threadIdx.x;
    const int bt  = blockIdx.y;
    const int dir = blockIdx.z & 1;
    const int g   = blockIdx.z >> 1;
    const long base = (long)bt * (1024 * 1024) + c;
    const long stride = dir ? -1024 : 1024;
    long idx = dir ? base + (long)(1023 - g * TCH) * 1024
                   : base + (long)(g * TCH) * 1024;
    const float w = -__expf(decay[c]);
    float a = 0.f, b = 0.f, p = -1e38f;

    float kq[8], vq[8];
#pragma unroll
    for (int j = 0; j < 8; ++j) {
        kq[j] = bf2f(kbuf[idx + j * stride]);
        vq[j] = bf2f(vbuf[idx + j * stride]);
    }
    for (int tb = 0; tb < TCH / 8; ++tb) {
        float kn[8], vn[8];
        if (tb < TCH / 8 - 1) {
#pragma unroll
            for (int j = 0; j < 8; ++j) {
                kn[j] = bf2f(kbuf[idx + (j + 8) * stride]);
                vn[j] = bf2f(vbuf[idx + (j + 8) * stride]);
            }
        }
#pragma unroll
        for (int j = 0; j < 8; ++j) {
            const float kk = kq[j], vv = vq[j];
            const float pw = p + w;
            const float q2 = fmaxf(pw, kk);
            const float f1 = __expf(pw - q2);
            const float f2 = __expf(kk - q2);
            a = f1 * a + f2 * vv;
            b = f1 * b + f2;
            p = q2;
        }
#pragma unroll
        for (int j = 0; j < 8; ++j) { kq[j] = kn[j]; vq[j] = vn[j]; }
        idx += 8 * stride;
    }
    const int sidx = (((dir * GCH + g) * 8 + bt) << 10) + c;
    sumA[sidx] = a; sumB[sidx] = b; sumP[sidx] = p;
}

__global__ __launch_bounds__(64)
void wkv_out(const u16* __restrict__ kbuf, const u16* __restrict__ vbuf,
             const float* __restrict__ decay, const float* __restrict__ uarr,
             const float* __restrict__ sumA, const float* __restrict__ sumB,
             const float* __restrict__ sumP,
             u16* __restrict__ wkvf, u16* __restrict__ wkvb)
{
    const int c   = blockIdx.x * 64 + threadIdx.x;
    const int bt  = blockIdx.y;
    const int dir = blockIdx.z & 1;
    const int g   = blockIdx.z >> 1;
    const long base = (long)bt * (1024 * 1024) + c;
    const long stride = dir ? -1024 : 1024;
    long idx = dir ? base + (long)(1023 - g * TCH) * 1024
                   : base + (long)(g * TCH) * 1024;
    u16* __restrict__ dst = dir ? wkvb : wkvf;

    const float w  = -__expf(decay[c]);
    const float uu = uarr[c];
    float a = 0.f, b = 0.f, p = -1e38f;
    for (int gg = 0; gg < g; ++gg) {
        const int sidx = (((dir * GCH + gg) * 8 + bt) << 10) + c;
        const float a2 = sumA[sidx], b2 = sumB[sidx], p2 = sumP[sidx];
        const float pd = p + w * (float)TCH;
        const float qq = fmaxf(pd, p2);
        const float x1 = __expf(pd - qq);
        const float x2 = __expf(p2 - qq);
        a = x1 * a + x2 * a2;
        b = x1 * b + x2 * b2;
        p = qq;
    }

    float kq[8], vq[8];
#pragma unroll
    for (int j = 0; j < 8; ++j) {
        kq[j] = bf2f(kbuf[idx + j * stride]);
        vq[j] = bf2f(vbuf[idx + j * stride]);
    }
    for (int tb = 0; tb < TCH / 8; ++tb) {
        float kn[8], vn[8];
        if (tb < TCH / 8 - 1) {
#pragma unroll
            for (int j = 0; j < 8; ++j) {
                kn[j] = bf2f(kbuf[idx + (j + 8) * stride]);
                vn[j] = bf2f(vbuf[idx + (j + 8) * stride]);
            }
        }
#pragma unroll
        for (int j = 0; j < 8; ++j) {
            const float kk = kq[j], vv = vq[j];
            const float uk = uu + kk;
            const float q1 = fmaxf(p, uk);
            const float e1 = __expf(p - q1);
            const float e2 = __expf(uk - q1);
            dst[idx + j * stride] = f2bf(__fdividef(e1 * a + e2 * vv, e1 * b + e2));
            const float pw = p + w;
            const float q2 = fmaxf(pw, kk);
            const float f1 = __expf(pw - q2);
            const float f2 = __expf(kk - q2);
            a = f1 * a + f2 * vv;
            b = f1 * b + f2;
            p = q2;
        }
#pragma unroll
        for (int j = 0; j < 8; ++j) { kq[j] = kn[j]; vq[j] = vn[j]; }
        idx += 8 * stride;
    }
}

// ---------------------------------------------------------------------------
// combine: rwkv = sigmoid(r_pre) * 0.5 * (wkv_f + wkv_b); in-place over wkv_f
// ---------------------------------------------------------------------------
__global__ __launch_bounds__(256)
void combine_kernel(u16* __restrict__ wkvf, const u16* __restrict__ wkvb,
                    const u16* __restrict__ rpre)
{
    const int i = blockIdx.x * 256 + threadIdx.x;
    ushort4 fv = ((const ushort4*)wkvf)[i];
    ushort4 bv = ((const ushort4*)wkvb)[i];
    ushort4 rv = ((const ushort4*)rpre)[i];
    ushort4 o;
    {
        float r0 = __fdividef(1.f, 1.f + __expf(-bf2f(rv.x)));
        float r1 = __fdividef(1.f, 1.f + __expf(-bf2f(rv.y)));
        float r2 = __fdividef(1.f, 1.f + __expf(-bf2f(rv.z)));
        float r3 = __fdividef(1.f, 1.f + __expf(-bf2f(rv.w)));
        o.x = f2bf(r0 * 0.5f * (bf2f(fv.x) + bf2f(bv.x)));
        o.y = f2bf(r1 * 0.5f * (bf2f(fv.y) + bf2f(bv.y)));
        o.z = f2bf(r2 * 0.5f * (bf2f(fv.z) + bf2f(bv.z)));
        o.w = f2bf(r3 * 0.5f * (bf2f(fv.w) + bf2f(bv.w)));
    }
    ((ushort4*)wkvf)[i] = o;
}

// ---------------------------------------------------------------------------
extern "C" void kernel_launch(void* const* d_in, const int* in_sizes, int n_in,
                              void* d_out, int out_size, void* d_ws, size_t ws_size,
                              hipStream_t stream)
{
    (void)in_sizes; (void)n_in; (void)out_size; (void)ws_size;
    const float* x     = (const float*)d_in[0];
    const float* ln1w  = (const float*)d_in[1];
    const float* ln1b  = (const float*)d_in[2];
    const float* ln2w  = (const float*)d_in[3];
    const float* ln2b  = (const float*)d_in[4];
    const float* Wr    = (const float*)d_in[5];
    const float* Wk    = (const float*)d_in[6];
    const float* Wv    = (const float*)d_in[7];
    const float* Wo    = (const float*)d_in[8];
    const float* decay = (const float*)d_in[9];
    const float* uarr  = (const float*)d_in[10];
    const float* Wfk   = (const float*)d_in[11];
    const float* Wfv   = (const float*)d_in[12];
    const float* Wfr   = (const float*)d_in[13];

    const int M = 8192, C = 1024, C4 = 4096;
    const size_t MB = 1024u * 1024u;
    char* ws = (char*)d_ws;
    float* X2   = (float*)(ws);              // [0,32)    x after time-mix (fp32)
    u16*  XN    = (u16*)(ws + 32 * MB);      // [32,48)   xn / xn2
    u16*  RP    = (u16*)(ws + 48 * MB);      // [48,64)   r_pre, later ffn sigmoid
    u16*  KB    = (u16*)(ws + 64 * MB);      // [64,80)   k
    u16*  VB    = (u16*)(ws + 80 * MB);      // [80,96)   v
    u16*  WKVF  = (u16*)(ws + 96 * MB);      // [96,112)  fwd wkv -> rwkv (in-place)
    u16*  WKVB  = (u16*)(ws + 112 * MB);     // [112,128) bwd wkv
    u16*  KK    = (u16*)(ws + 64 * MB);      // [64,128)  ffn relu^2 key (reuse)
    u16*  WrB   = (u16*)(ws + 128 * MB);
    u16*  WkB   = (u16*)(ws + 130 * MB);
    u16*  WvB   = (u16*)(ws + 132 * MB);
    u16*  WoB   = (u16*)(ws + 134 * MB);
    u16*  WfrB  = (u16*)(ws + 136 * MB);
    u16*  WfkB  = (u16*)(ws + 138 * MB);
    u16*  WfvB  = (u16*)(ws + 146 * MB);
    float* sumA = (float*)(ws);              // scan summaries in X2 region
    float* sumB = (float*)(ws + 4 * MB);
    float* sumP = (float*)(ws + 8 * MB);

    const dim3 blk(256);
    const dim3 gC(C / 128, M / 128);
    const dim3 gC4(C4 / 128, M / 128);
    const int n4_1M = C * C / 4, n4_4M = C * C4 / 4;

    f2bf_kernel<<<dim3(n4_1M / 256), blk, 0, stream>>>(Wr,  WrB,  n4_1M);
    f2bf_kernel<<<dim3(n4_1M / 256), blk, 0, stream>>>(Wk,  WkB,  n4_1M);
    f2bf_kernel<<<dim3(n4_1M / 256), blk, 0, stream>>>(Wv,  WvB,  n4_1M);
    f2bf_kernel<<<dim3(n4_1M / 256), blk, 0, stream>>>(Wo,  WoB,  n4_1M);
    f2bf_kernel<<<dim3(n4_1M / 256), blk, 0, stream>>>(Wfr, WfrB, n4_1M);
    f2bf_kernel<<<dim3(n4_4M / 256), blk, 0, stream>>>(Wfk, WfkB, n4_4M);
    f2bf_kernel<<<dim3(n4_4M / 256), blk, 0, stream>>>(Wfv, WfvB, n4_4M);

    ln_kernel<<<dim3(M), blk, 0, stream>>>(x, ln1w, ln1b, XN);
    gemm_bt<0><<<gC, blk, 0, stream>>>(XN, WrB, M, C, C, RP, nullptr, nullptr);
    gemm_bt<0><<<gC, blk, 0, stream>>>(XN, WkB, M, C, C, KB, nullptr, nullptr);
    gemm_bt<0><<<gC, blk, 0, stream>>>(XN, WvB, M, C, C, VB, nullptr, nullptr);
    wkv_sum<<<dim3(16, 8, 2 * GCH), dim3(64), 0, stream>>>(KB, VB, decay,
                                                           sumA, sumB, sumP);
    wkv_out<<<dim3(16, 8, 2 * GCH), dim3(64), 0, stream>>>(KB, VB, decay, uarr,
                                                           sumA, sumB, sumP,
                                                           WKVF, WKVB);
    combine_kernel<<<dim3(M * C / 4 / 256), blk, 0, stream>>>(WKVF, WKVB, RP);
    gemm_bt<1><<<gC, blk, 0, stream>>>(WKVF, WoB, M, C, C, X2, x, nullptr);
    ln_kernel<<<dim3(M), blk, 0, stream>>>(X2, ln2w, ln2b, XN);
    gemm_bt<2><<<gC4, blk, 0, stream>>>(XN, WfkB, M, C4, C, KK, nullptr, nullptr);
    gemm_bt<3><<<gC, blk, 0, stream>>>(XN, WfrB, M, C, C, RP, nullptr, nullptr);
    gemm_bt<4><<<gC, blk, 0, stream>>>(KK, WfvB, M, C, C4, d_out, X2, RP);
}

// Round 5
// 488.851 us; speedup vs baseline: 1.3337x; 1.0945x over previous
//
#include <hip/hip_runtime.h>
#include <cstdint>
#include <cstddef>

typedef unsigned short u16;
typedef __bf16 bf16_t;
typedef bf16_t bf16x8 __attribute__((ext_vector_type(8)));
typedef float f32x4 __attribute__((ext_vector_type(4)));

#define GCH 16          // scan chunks
#define TCH 64          // steps per chunk (1024 / GCH)

static __device__ __forceinline__ float bf2f(u16 v) {
    union { unsigned int u; float f; } cv;
    cv.u = ((unsigned int)v) << 16;
    return cv.f;
}
static __device__ __forceinline__ u16 f2bf(float f) {
    union { float f; unsigned int u; } cv;
    cv.f = f;
    unsigned int r = 0x7fffu + ((cv.u >> 16) & 1u);
    return (u16)((cv.u + r) >> 16);
}

// ---------------------------------------------------------------------------
// fp32 -> bf16 conversion (weights), 4 elems/thread
// ---------------------------------------------------------------------------
__global__ __launch_bounds__(256)
void f2bf_kernel(const float* __restrict__ in, u16* __restrict__ out, int n4)
{
    const int i = blockIdx.x * 256 + threadIdx.x;
    if (i < n4) {
        float4 f = ((const float4*)in)[i];
        ushort4 o;
        o.x = f2bf(f.x); o.y = f2bf(f.y); o.z = f2bf(f.z); o.w = f2bf(f.w);
        ((ushort4*)out)[i] = o;
    }
}

// ---------------------------------------------------------------------------
// LayerNorm over rows of 1024, fp32 in, bf16 out. 256 thr/row.
// ---------------------------------------------------------------------------
__global__ __launch_bounds__(256)
void ln_kernel(const float* __restrict__ xin, const float* __restrict__ w,
               const float* __restrict__ b, u16* __restrict__ out)
{
    const int row = blockIdx.x;
    const int tid = threadIdx.x;
    const float4 f = ((const float4*)(xin + (size_t)row * 1024))[tid];
    float vals[4] = { f.x, f.y, f.z, f.w };
    float s  = vals[0] + vals[1] + vals[2] + vals[3];
    float ss = vals[0]*vals[0] + vals[1]*vals[1] + vals[2]*vals[2] + vals[3]*vals[3];
    for (int off = 32; off; off >>= 1) {
        s  += __shfl_down(s, off, 64);
        ss += __shfl_down(ss, off, 64);
    }
    __shared__ float redS[4], redQ[4];
    if ((tid & 63) == 0) { redS[tid >> 6] = s; redQ[tid >> 6] = ss; }
    __syncthreads();
    s  = redS[0] + redS[1] + redS[2] + redS[3];
    ss = redQ[0] + redQ[1] + redQ[2] + redQ[3];
    const float mu  = s * (1.f / 1024.f);
    const float var = ss * (1.f / 1024.f) - mu * mu;
    const float rs  = rsqrtf(var + 1e-5f);
    const float4 wv = ((const float4*)w)[tid];
    const float4 bv = ((const float4*)b)[tid];
    ushort4 o;
    o.x = f2bf((vals[0] - mu) * rs * wv.x + bv.x);
    o.y = f2bf((vals[1] - mu) * rs * wv.y + bv.y);
    o.z = f2bf((vals[2] - mu) * rs * wv.z + bv.z);
    o.w = f2bf((vals[3] - mu) * rs * wv.w + bv.w);
    ((ushort4*)(out + (size_t)row * 1024))[tid] = o;
}

// ---------------------------------------------------------------------------
// GEMM: out[M,N] = A[M,K] @ B[N,K]^T  (bf16 in, K contiguous), m97 recipe
// + XOR bank-conflict swizzle (LDS[row][g] = global[row][g ^ (row&7)])
// + transposed grid: blockIdx.x = M-panel, blockIdx.y = N-panel, so
//   XCD (≈ linear%8) = mx%8 -> A-panels are L2-resident and shared across
//   the XCD's N-panels (cuts A re-fetch ~8x vs x-fastest-N mapping).
// EPI: 0: bf16(acc); 1: f32(aux1)+acc -> f32; 2: bf16(relu(acc)^2);
//      3: bf16(sigmoid(acc)); 4: f32(aux1)+bf16(aux2)*acc -> f32
//      5: QKV fused split (N=3072): seg0->outp, seg1->aux1, seg2->aux2 (bf16)
//      6: FFN-in fused (N=5120): n<4096: relu^2 -> outp (stride 4096);
//         else sigmoid -> aux1 (stride 1024)
// ---------------------------------------------------------------------------
template<int EPI>
__global__ __launch_bounds__(256)
void gemm_bt(const u16* __restrict__ A, const u16* __restrict__ B,
             int M, int N, int K,
             void* __restrict__ outp,
             const void* __restrict__ aux1, const void* __restrict__ aux2)
{
    __shared__ u16 lA[128 * 64];
    __shared__ u16 lB[128 * 64];
    const int tid  = threadIdx.x;
    const int wave = tid >> 6;
    const int lane = tid & 63;
    const int q    = lane >> 4;
    const int l16  = lane & 15;
    const long mBase = (long)blockIdx.x * 128;   // transposed grid
    const long nBase = (long)blockIdx.y * 128;
    const int wm = (wave >> 1) * 64;
    const int wn = (wave & 1) * 64;

    f32x4 acc[4][4];
#pragma unroll
    for (int i = 0; i < 4; ++i)
#pragma unroll
        for (int j = 0; j < 4; ++j)
#pragma unroll
            for (int r = 0; r < 4; ++r) acc[i][j][r] = 0.f;

    const int srow = tid >> 3;
    const int scol = ((tid & 7) ^ (srow & 7)) * 8;   // XOR swizzle at staging
    const int ldsW = wave * 512;
    const int swz = l16 & 7;

    for (int kb = 0; kb < K; kb += 64) {
        __syncthreads();
#pragma unroll
        for (int c = 0; c < 4; ++c) {
            const int row = c * 32 + srow;
            const u16* ga = A + (mBase + row) * (long)K + kb + scol;
            const u16* gb = B + (nBase + row) * (long)K + kb + scol;
            __builtin_amdgcn_global_load_lds(
                (const __attribute__((address_space(1))) void*)ga,
                (__attribute__((address_space(3))) void*)(lA + c * 2048 + ldsW),
                16, 0, 0);
            __builtin_amdgcn_global_load_lds(
                (const __attribute__((address_space(1))) void*)gb,
                (__attribute__((address_space(3))) void*)(lB + c * 2048 + ldsW),
                16, 0, 0);
        }
        __syncthreads();
#pragma unroll
        for (int ks = 0; ks < 2; ++ks) {
            const int grp = ((ks * 4 + q) ^ swz) * 8;   // undo swizzle
            bf16x8 af[4], bfm[4];
#pragma unroll
            for (int i = 0; i < 4; ++i) {
                af[i]  = *(const bf16x8*)(lA + (wm + i * 16 + l16) * 64 + grp);
                bfm[i] = *(const bf16x8*)(lB + (wn + i * 16 + l16) * 64 + grp);
            }
#pragma unroll
            for (int i = 0; i < 4; ++i)
#pragma unroll
                for (int j = 0; j < 4; ++j)
                    acc[i][j] = __builtin_amdgcn_mfma_f32_16x16x32_bf16(
                        af[i], bfm[j], acc[i][j], 0, 0, 0);
        }
    }

    // epilogue: C/D layout col=lane&15, row=(lane>>4)*4+reg  [m89/m91]
    if (EPI == 5 || EPI == 6) {
        // block-uniform output segment select
        u16* optr; long sN, cb;
        if (EPI == 5) {
            const long seg = nBase >> 10;
            optr = (u16*)(seg == 0 ? outp
                        : seg == 1 ? (void*)aux1 : (void*)aux2);
            sN = 1024; cb = (nBase & 1023) + wn + l16;
        } else {
            if (nBase < 4096) { optr = (u16*)outp; sN = 4096; cb = nBase + wn + l16; }
            else { optr = (u16*)aux1; sN = 1024; cb = (nBase - 4096) + wn + l16; }
        }
#pragma unroll
        for (int i = 0; i < 4; ++i)
#pragma unroll
            for (int r = 0; r < 4; ++r) {
                const long row = mBase + wm + i * 16 + q * 4 + r;
                const long rowOff = row * sN + cb;
#pragma unroll
                for (int j = 0; j < 4; ++j) {
                    const float val = acc[i][j][r];
                    float t;
                    if (EPI == 5) t = val;
                    else if (nBase < 4096) t = val > 0.f ? val * val : 0.f;
                    else t = __fdividef(1.f, 1.f + __expf(-val));
                    optr[rowOff + j * 16] = f2bf(t);
                }
            }
    } else {
        const long colBase = nBase + wn + l16;
#pragma unroll
        for (int i = 0; i < 4; ++i) {
#pragma unroll
            for (int r = 0; r < 4; ++r) {
                const long row = mBase + wm + i * 16 + q * 4 + r;
                const long rowOff = row * (long)N;
#pragma unroll
                for (int j = 0; j < 4; ++j) {
                    const long idx = rowOff + colBase + j * 16;
                    const float val = acc[i][j][r];
                    if (EPI == 0) {
                        ((u16*)outp)[idx] = f2bf(val);
                    } else if (EPI == 1) {
                        ((float*)outp)[idx] = ((const float*)aux1)[idx] + val;
                    } else if (EPI == 2) {
                        const float t = val > 0.f ? val * val : 0.f;
                        ((u16*)outp)[idx] = f2bf(t);
                    } else if (EPI == 3) {
                        const float sg = __fdividef(1.f, 1.f + __expf(-val));
                        ((u16*)outp)[idx] = f2bf(sg);
                    } else {
                        const float t = ((const float*)aux1)[idx]
                                      + bf2f(((const u16*)aux2)[idx]) * val;
                        ((float*)outp)[idx] = t;
                    }
                }
            }
        }
    }
}

// ---------------------------------------------------------------------------
// Chunked WKV scan (associative (a,b,p) monoid). Phase 1: per-chunk summary.
// Phase 2: fold preceding summaries, emit own chunk's outputs.
// grid (16, B, 2*GCH): z&1 = dir, z>>1 = chunk. One wave / 64 channels.
// ---------------------------------------------------------------------------
__global__ __launch_bounds__(64)
void wkv_sum(const u16* __restrict__ kbuf, const u16* __restrict__ vbuf,
             const float* __restrict__ decay,
             float* __restrict__ sumA, float* __restrict__ sumB,
             float* __restrict__ sumP)
{
    const int c   = blockIdx.x * 64 + threadIdx.x;
    const int bt  = blockIdx.y;
    const int dir = blockIdx.z & 1;
    const int g   = blockIdx.z >> 1;
    const long base = (long)bt * (1024 * 1024) + c;
    const long stride = dir ? -1024 : 1024;
    long idx = dir ? base + (long)(1023 - g * TCH) * 1024
                   : base + (long)(g * TCH) * 1024;
    const float w = -__expf(decay[c]);
    float a = 0.f, b = 0.f, p = -1e38f;

    float kq[8], vq[8];
#pragma unroll
    for (int j = 0; j < 8; ++j) {
        kq[j] = bf2f(kbuf[idx + j * stride]);
        vq[j] = bf2f(vbuf[idx + j * stride]);
    }
    for (int tb = 0; tb < TCH / 8; ++tb) {
        float kn[8], vn[8];
        if (tb < TCH / 8 - 1) {
#pragma unroll
            for (int j = 0; j < 8; ++j) {
                kn[j] = bf2f(kbuf[idx + (j + 8) * stride]);
                vn[j] = bf2f(vbuf[idx + (j + 8) * stride]);
            }
        }
#pragma unroll
        for (int j = 0; j < 8; ++j) {
            const float kk = kq[j], vv = vq[j];
            const float pw = p + w;
            const float q2 = fmaxf(pw, kk);
            const float f1 = __expf(pw - q2);
            const float f2 = __expf(kk - q2);
            a = f1 * a + f2 * vv;
            b = f1 * b + f2;
            p = q2;
        }
#pragma unroll
        for (int j = 0; j < 8; ++j) { kq[j] = kn[j]; vq[j] = vn[j]; }
        idx += 8 * stride;
    }
    const int sidx = (((dir * GCH + g) * 8 + bt) << 10) + c;
    sumA[sidx] = a; sumB[sidx] = b; sumP[sidx] = p;
}

__global__ __launch_bounds__(64)
void wkv_out(const u16* __restrict__ kbuf, const u16* __restrict__ vbuf,
             const float* __restrict__ decay, const float* __restrict__ uarr,
             const float* __restrict__ sumA, const float* __restrict__ sumB,
             const float* __restrict__ sumP,
             u16* __restrict__ wkvf, u16* __restrict__ wkvb)
{
    const int c   = blockIdx.x * 64 + threadIdx.x;
    const int bt  = blockIdx.y;
    const int dir = blockIdx.z & 1;
    const int g   = blockIdx.z >> 1;
    const long base = (long)bt * (1024 * 1024) + c;
    const long stride = dir ? -1024 : 1024;
    long idx = dir ? base + (long)(1023 - g * TCH) * 1024
                   : base + (long)(g * TCH) * 1024;
    u16* __restrict__ dst = dir ? wkvb : wkvf;

    const float w  = -__expf(decay[c]);
    const float uu = uarr[c];
    float a = 0.f, b = 0.f, p = -1e38f;
    for (int gg = 0; gg < g; ++gg) {
        const int sidx = (((dir * GCH + gg) * 8 + bt) << 10) + c;
        const float a2 = sumA[sidx], b2 = sumB[sidx], p2 = sumP[sidx];
        const float pd = p + w * (float)TCH;
        const float qq = fmaxf(pd, p2);
        const float x1 = __expf(pd - qq);
        const float x2 = __expf(p2 - qq);
        a = x1 * a + x2 * a2;
        b = x1 * b + x2 * b2;
        p = qq;
    }

    float kq[8], vq[8];
#pragma unroll
    for (int j = 0; j < 8; ++j) {
        kq[j] = bf2f(kbuf[idx + j * stride]);
        vq[j] = bf2f(vbuf[idx + j * stride]);
    }
    for (int tb = 0; tb < TCH / 8; ++tb) {
        float kn[8], vn[8];
        if (tb < TCH / 8 - 1) {
#pragma unroll
            for (int j = 0; j < 8; ++j) {
                kn[j] = bf2f(kbuf[idx + (j + 8) * stride]);
                vn[j] = bf2f(vbuf[idx + (j + 8) * stride]);
            }
        }
#pragma unroll
        for (int j = 0; j < 8; ++j) {
            const float kk = kq[j], vv = vq[j];
            const float uk = uu + kk;
            const float q1 = fmaxf(p, uk);
            const float e1 = __expf(p - q1);
            const float e2 = __expf(uk - q1);
            dst[idx + j * stride] = f2bf(__fdividef(e1 * a + e2 * vv, e1 * b + e2));
            const float pw = p + w;
            const float q2 = fmaxf(pw, kk);
            const float f1 = __expf(pw - q2);
            const float f2 = __expf(kk - q2);
            a = f1 * a + f2 * vv;
            b = f1 * b + f2;
            p = q2;
        }
#pragma unroll
        for (int j = 0; j < 8; ++j) { kq[j] = kn[j]; vq[j] = vn[j]; }
        idx += 8 * stride;
    }
}

// ---------------------------------------------------------------------------
// combine: rwkv = sigmoid(r_pre) * 0.5 * (wkv_f + wkv_b); in-place over wkv_f
// ---------------------------------------------------------------------------
__global__ __launch_bounds__(256)
void combine_kernel(u16* __restrict__ wkvf, const u16* __restrict__ wkvb,
                    const u16* __restrict__ rpre)
{
    const int i = blockIdx.x * 256 + threadIdx.x;
    ushort4 fv = ((const ushort4*)wkvf)[i];
    ushort4 bv = ((const ushort4*)wkvb)[i];
    ushort4 rv = ((const ushort4*)rpre)[i];
    ushort4 o;
    {
        float r0 = __fdividef(1.f, 1.f + __expf(-bf2f(rv.x)));
        float r1 = __fdividef(1.f, 1.f + __expf(-bf2f(rv.y)));
        float r2 = __fdividef(1.f, 1.f + __expf(-bf2f(rv.z)));
        float r3 = __fdividef(1.f, 1.f + __expf(-bf2f(rv.w)));
        o.x = f2bf(r0 * 0.5f * (bf2f(fv.x) + bf2f(bv.x)));
        o.y = f2bf(r1 * 0.5f * (bf2f(fv.y) + bf2f(bv.y)));
        o.z = f2bf(r2 * 0.5f * (bf2f(fv.z) + bf2f(bv.z)));
        o.w = f2bf(r3 * 0.5f * (bf2f(fv.w) + bf2f(bv.w)));
    }
    ((ushort4*)wkvf)[i] = o;
}

// ---------------------------------------------------------------------------
extern "C" void kernel_launch(void* const* d_in, const int* in_sizes, int n_in,
                              void* d_out, int out_size, void* d_ws, size_t ws_size,
                              hipStream_t stream)
{
    (void)in_sizes; (void)n_in; (void)out_size; (void)ws_size;
    const float* x     = (const float*)d_in[0];
    const float* ln1w  = (const float*)d_in[1];
    const float* ln1b  = (const float*)d_in[2];
    const float* ln2w  = (const float*)d_in[3];
    const float* ln2b  = (const float*)d_in[4];
    const float* Wr    = (const float*)d_in[5];
    const float* Wk    = (const float*)d_in[6];
    const float* Wv    = (const float*)d_in[7];
    const float* Wo    = (const float*)d_in[8];
    const float* decay = (const float*)d_in[9];
    const float* uarr  = (const float*)d_in[10];
    const float* Wfk   = (const float*)d_in[11];
    const float* Wfv   = (const float*)d_in[12];
    const float* Wfr   = (const float*)d_in[13];

    const int M = 8192, C = 1024, C4 = 4096;
    const size_t MB = 1024u * 1024u;
    char* ws = (char*)d_ws;
    float* X2   = (float*)(ws);              // [0,32)    x after time-mix (fp32)
    u16*  XN    = (u16*)(ws + 32 * MB);      // [32,48)   xn / xn2
    u16*  RP    = (u16*)(ws + 48 * MB);      // [48,64)   r_pre, later ffn sigmoid
    u16*  KB    = (u16*)(ws + 64 * MB);      // [64,80)   k
    u16*  VB    = (u16*)(ws + 80 * MB);      // [80,96)   v
    u16*  WKVF  = (u16*)(ws + 96 * MB);      // [96,112)  fwd wkv -> rwkv (in-place)
    u16*  WKVB  = (u16*)(ws + 112 * MB);     // [112,128) bwd wkv
    u16*  KK    = (u16*)(ws + 64 * MB);      // [64,128)  ffn relu^2 key (reuse)
    // bf16 weights: Wr|Wk|Wv contiguous (fused QKV B, N=3072);
    //               Wfk|Wfr contiguous (fused FFN-in B, N=5120)
    u16*  WrB   = (u16*)(ws + 128 * MB);     // 2 MB
    u16*  WkB   = (u16*)(ws + 130 * MB);     // 2 MB
    u16*  WvB   = (u16*)(ws + 132 * MB);     // 2 MB
    u16*  WoB   = (u16*)(ws + 134 * MB);     // 2 MB
    u16*  WfkB  = (u16*)(ws + 136 * MB);     // 8 MB
    u16*  WfrB  = (u16*)(ws + 144 * MB);     // 2 MB
    u16*  WfvB  = (u16*)(ws + 146 * MB);     // 8 MB -> ends 154 MB
    float* sumA = (float*)(ws);              // scan summaries in X2 region
    float* sumB = (float*)(ws + 4 * MB);
    float* sumP = (float*)(ws + 8 * MB);

    const dim3 blk(256);
    const int n4_1M = C * C / 4, n4_4M = C * C4 / 4;

    f2bf_kernel<<<dim3(n4_1M / 256), blk, 0, stream>>>(Wr,  WrB,  n4_1M);
    f2bf_kernel<<<dim3(n4_1M / 256), blk, 0, stream>>>(Wk,  WkB,  n4_1M);
    f2bf_kernel<<<dim3(n4_1M / 256), blk, 0, stream>>>(Wv,  WvB,  n4_1M);
    f2bf_kernel<<<dim3(n4_1M / 256), blk, 0, stream>>>(Wo,  WoB,  n4_1M);
    f2bf_kernel<<<dim3(n4_4M / 256), blk, 0, stream>>>(Wfk, WfkB, n4_4M);
    f2bf_kernel<<<dim3(n4_1M / 256), blk, 0, stream>>>(Wfr, WfrB, n4_1M);
    f2bf_kernel<<<dim3(n4_4M / 256), blk, 0, stream>>>(Wfv, WfvB, n4_4M);

    ln_kernel<<<dim3(M), blk, 0, stream>>>(x, ln1w, ln1b, XN);
    // fused QKV: N = 3072, B = [Wr;Wk;Wv]
    gemm_bt<5><<<dim3(M / 128, 3 * C / 128), blk, 0, stream>>>(
        XN, WrB, M, 3 * C, C, RP, KB, VB);
    wkv_sum<<<dim3(16, 8, 2 * GCH), dim3(64), 0, stream>>>(KB, VB, decay,
                                                           sumA, sumB, sumP);
    wkv_out<<<dim3(16, 8, 2 * GCH), dim3(64), 0, stream>>>(KB, VB, decay, uarr,
                                                           sumA, sumB, sumP,
                                                           WKVF, WKVB);
    combine_kernel<<<dim3(M * C / 4 / 256), blk, 0, stream>>>(WKVF, WKVB, RP);
    gemm_bt<1><<<dim3(M / 128, C / 128), blk, 0, stream>>>(
        WKVF, WoB, M, C, C, X2, x, nullptr);
    ln_kernel<<<dim3(M), blk, 0, stream>>>(X2, ln2w, ln2b, XN);
    // fused FFN-in: N = 5120, B = [Wfk;Wfr]; relu^2 -> KK, sigmoid -> RP
    gemm_bt<6><<<dim3(M / 128, 5 * C / 128), blk, 0, stream>>>(
        XN, WfkB, M, 5 * C, C, KK, RP, nullptr);
    gemm_bt<4><<<dim3(M / 128, C / 128), blk, 0, stream>>>(
        KK, WfvB, M, C, C4, d_out, X2, RP);
}

// Round 6
// 462.078 us; speedup vs baseline: 1.4109x; 1.0579x over previous
//
#include <hip/hip_runtime.h>
#include <cstdint>
#include <cstddef>

typedef unsigned short u16;
typedef __bf16 bf16_t;
typedef bf16_t bf16x8 __attribute__((ext_vector_type(8)));
typedef float f32x4 __attribute__((ext_vector_type(4)));

#define GCH 16          // scan chunks
#define TCH 64          // steps per chunk (1024 / GCH)

static __device__ __forceinline__ float bf2f(u16 v) {
    union { unsigned int u; float f; } cv;
    cv.u = ((unsigned int)v) << 16;
    return cv.f;
}
static __device__ __forceinline__ u16 f2bf(float f) {
    union { float f; unsigned int u; } cv;
    cv.f = f;
    unsigned int r = 0x7fffu + ((cv.u >> 16) & 1u);
    return (u16)((cv.u + r) >> 16);
}

// ---------------------------------------------------------------------------
// fp32 -> bf16 for all 7 weight tensors in one launch. grid (maxBlocks, 7).
// ---------------------------------------------------------------------------
struct F2BFSegs { const float* src[7]; u16* dst[7]; int n4[7]; };

__global__ __launch_bounds__(256)
void f2bf_all(F2BFSegs s)
{
    const int seg = blockIdx.y;
    const int i = blockIdx.x * 256 + threadIdx.x;
    if (i < s.n4[seg]) {
        float4 f = ((const float4*)s.src[seg])[i];
        ushort4 o;
        o.x = f2bf(f.x); o.y = f2bf(f.y); o.z = f2bf(f.z); o.w = f2bf(f.w);
        ((ushort4*)s.dst[seg])[i] = o;
    }
}

// ---------------------------------------------------------------------------
// LayerNorm over rows of 1024, fp32 or bf16 in, bf16 out. 256 thr/row.
// ---------------------------------------------------------------------------
template<int BF16IN>
__global__ __launch_bounds__(256)
void ln_kernel(const void* __restrict__ xin, const float* __restrict__ w,
               const float* __restrict__ b, u16* __restrict__ out)
{
    const int row = blockIdx.x;
    const int tid = threadIdx.x;
    float vals[4];
    if (BF16IN) {
        const ushort4 uv = ((const ushort4*)((const u16*)xin + (size_t)row * 1024))[tid];
        vals[0] = bf2f(uv.x); vals[1] = bf2f(uv.y);
        vals[2] = bf2f(uv.z); vals[3] = bf2f(uv.w);
    } else {
        const float4 f = ((const float4*)((const float*)xin + (size_t)row * 1024))[tid];
        vals[0] = f.x; vals[1] = f.y; vals[2] = f.z; vals[3] = f.w;
    }
    float s  = vals[0] + vals[1] + vals[2] + vals[3];
    float ss = vals[0]*vals[0] + vals[1]*vals[1] + vals[2]*vals[2] + vals[3]*vals[3];
    for (int off = 32; off; off >>= 1) {
        s  += __shfl_down(s, off, 64);
        ss += __shfl_down(ss, off, 64);
    }
    __shared__ float redS[4], redQ[4];
    if ((tid & 63) == 0) { redS[tid >> 6] = s; redQ[tid >> 6] = ss; }
    __syncthreads();
    s  = redS[0] + redS[1] + redS[2] + redS[3];
    ss = redQ[0] + redQ[1] + redQ[2] + redQ[3];
    const float mu  = s * (1.f / 1024.f);
    const float var = ss * (1.f / 1024.f) - mu * mu;
    const float rs  = rsqrtf(var + 1e-5f);
    const float4 wv = ((const float4*)w)[tid];
    const float4 bv = ((const float4*)b)[tid];
    ushort4 o;
    o.x = f2bf((vals[0] - mu) * rs * wv.x + bv.x);
    o.y = f2bf((vals[1] - mu) * rs * wv.y + bv.y);
    o.z = f2bf((vals[2] - mu) * rs * wv.z + bv.z);
    o.w = f2bf((vals[3] - mu) * rs * wv.w + bv.w);
    ((ushort4*)(out + (size_t)row * 1024))[tid] = o;
}

// ---------------------------------------------------------------------------
// GEMM: out[M,N] = A[M,K] @ B[N,K]^T  (bf16 in, K contiguous), m97 recipe
// + XOR bank-conflict swizzle + transposed grid (x=M-panel for XCD locality).
// EPI: 1: bf16(f32(aux1)+acc) -> u16 (residual, aux1 = x fp32)
//      4: f32: bf16(aux1) + bf16(aux2)*acc -> float (final)
//      5: QKV fused split (N=3072): seg0->outp, seg1->aux1, seg2->aux2 (bf16)
//      6: FFN-in fused (N=5120): n<4096: relu^2 -> outp (stride 4096);
//         else sigmoid -> aux1 (stride 1024)
// ---------------------------------------------------------------------------
template<int EPI>
__global__ __launch_bounds__(256)
void gemm_bt(const u16* __restrict__ A, const u16* __restrict__ B,
             int M, int N, int K,
             void* __restrict__ outp,
             const void* __restrict__ aux1, const void* __restrict__ aux2)
{
    __shared__ u16 lA[128 * 64];
    __shared__ u16 lB[128 * 64];
    const int tid  = threadIdx.x;
    const int wave = tid >> 6;
    const int lane = tid & 63;
    const int q    = lane >> 4;
    const int l16  = lane & 15;
    const long mBase = (long)blockIdx.x * 128;   // transposed grid
    const long nBase = (long)blockIdx.y * 128;
    const int wm = (wave >> 1) * 64;
    const int wn = (wave & 1) * 64;

    f32x4 acc[4][4];
#pragma unroll
    for (int i = 0; i < 4; ++i)
#pragma unroll
        for (int j = 0; j < 4; ++j)
#pragma unroll
            for (int r = 0; r < 4; ++r) acc[i][j][r] = 0.f;

    const int srow = tid >> 3;
    const int scol = ((tid & 7) ^ (srow & 7)) * 8;   // XOR swizzle at staging
    const int ldsW = wave * 512;
    const int swz = l16 & 7;

    for (int kb = 0; kb < K; kb += 64) {
        __syncthreads();
#pragma unroll
        for (int c = 0; c < 4; ++c) {
            const int row = c * 32 + srow;
            const u16* ga = A + (mBase + row) * (long)K + kb + scol;
            const u16* gb = B + (nBase + row) * (long)K + kb + scol;
            __builtin_amdgcn_global_load_lds(
                (const __attribute__((address_space(1))) void*)ga,
                (__attribute__((address_space(3))) void*)(lA + c * 2048 + ldsW),
                16, 0, 0);
            __builtin_amdgcn_global_load_lds(
                (const __attribute__((address_space(1))) void*)gb,
                (__attribute__((address_space(3))) void*)(lB + c * 2048 + ldsW),
                16, 0, 0);
        }
        __syncthreads();
#pragma unroll
        for (int ks = 0; ks < 2; ++ks) {
            const int grp = ((ks * 4 + q) ^ swz) * 8;   // undo swizzle
            bf16x8 af[4], bfm[4];
#pragma unroll
            for (int i = 0; i < 4; ++i) {
                af[i]  = *(const bf16x8*)(lA + (wm + i * 16 + l16) * 64 + grp);
                bfm[i] = *(const bf16x8*)(lB + (wn + i * 16 + l16) * 64 + grp);
            }
#pragma unroll
            for (int i = 0; i < 4; ++i)
#pragma unroll
                for (int j = 0; j < 4; ++j)
                    acc[i][j] = __builtin_amdgcn_mfma_f32_16x16x32_bf16(
                        af[i], bfm[j], acc[i][j], 0, 0, 0);
        }
    }

    // epilogue: C/D layout col=lane&15, row=(lane>>4)*4+reg  [m89/m91]
    if (EPI == 5 || EPI == 6) {
        u16* optr; long sN, cb;
        if (EPI == 5) {
            const long seg = nBase >> 10;
            optr = (u16*)(seg == 0 ? outp
                        : seg == 1 ? (void*)aux1 : (void*)aux2);
            sN = 1024; cb = (nBase & 1023) + wn + l16;
        } else {
            if (nBase < 4096) { optr = (u16*)outp; sN = 4096; cb = nBase + wn + l16; }
            else { optr = (u16*)aux1; sN = 1024; cb = (nBase - 4096) + wn + l16; }
        }
#pragma unroll
        for (int i = 0; i < 4; ++i)
#pragma unroll
            for (int r = 0; r < 4; ++r) {
                const long row = mBase + wm + i * 16 + q * 4 + r;
                const long rowOff = row * sN + cb;
#pragma unroll
                for (int j = 0; j < 4; ++j) {
                    const float val = acc[i][j][r];
                    float t;
                    if (EPI == 5) t = val;
                    else if (nBase < 4096) t = val > 0.f ? val * val : 0.f;
                    else t = __fdividef(1.f, 1.f + __expf(-val));
                    optr[rowOff + j * 16] = f2bf(t);
                }
            }
    } else {
        const long colBase = nBase + wn + l16;
#pragma unroll
        for (int i = 0; i < 4; ++i) {
#pragma unroll
            for (int r = 0; r < 4; ++r) {
                const long row = mBase + wm + i * 16 + q * 4 + r;
                const long rowOff = row * (long)N;
#pragma unroll
                for (int j = 0; j < 4; ++j) {
                    const long idx = rowOff + colBase + j * 16;
                    const float val = acc[i][j][r];
                    if (EPI == 1) {
                        ((u16*)outp)[idx] = f2bf(((const float*)aux1)[idx] + val);
                    } else {
                        const float t = bf2f(((const u16*)aux1)[idx])
                                      + bf2f(((const u16*)aux2)[idx]) * val;
                        ((float*)outp)[idx] = t;
                    }
                }
            }
        }
    }
}

// ---------------------------------------------------------------------------
// Chunked WKV scan, phase 1: per-chunk (a,b,p) summary, both dirs.
// grid (16, B, 2*GCH): z&1 = dir, z>>1 = chunk. One wave / 64 channels.
// One-exp step: q=max(x,y) => one of exp(x-q),exp(y-q) is 1.
// ---------------------------------------------------------------------------
__global__ __launch_bounds__(64)
void wkv_sum(const u16* __restrict__ kbuf, const u16* __restrict__ vbuf,
             const float* __restrict__ decay,
             float* __restrict__ sumA, float* __restrict__ sumB,
             float* __restrict__ sumP)
{
    const int c   = blockIdx.x * 64 + threadIdx.x;
    const int bt  = blockIdx.y;
    const int dir = blockIdx.z & 1;
    const int g   = blockIdx.z >> 1;
    const long base = (long)bt * (1024 * 1024) + c;
    const long stride = dir ? -1024 : 1024;
    long idx = dir ? base + (long)(1023 - g * TCH) * 1024
                   : base + (long)(g * TCH) * 1024;
    const float w = -__expf(decay[c]);
    float a = 0.f, b = 0.f, p = -1e38f;

    float kq[8], vq[8];
#pragma unroll
    for (int j = 0; j < 8; ++j) {
        kq[j] = bf2f(kbuf[idx + j * stride]);
        vq[j] = bf2f(vbuf[idx + j * stride]);
    }
    for (int tb = 0; tb < TCH / 8; ++tb) {
        float kn[8], vn[8];
        if (tb < TCH / 8 - 1) {
#pragma unroll
            for (int j = 0; j < 8; ++j) {
                kn[j] = bf2f(kbuf[idx + (j + 8) * stride]);
                vn[j] = bf2f(vbuf[idx + (j + 8) * stride]);
            }
        }
#pragma unroll
        for (int j = 0; j < 8; ++j) {
            const float kk = kq[j], vv = vq[j];
            const float pw = p + w;
            const float d  = pw - kk;
            const float e  = __expf(-fabsf(d));
            const float f1 = d >= 0.f ? 1.f : e;
            const float f2 = d >= 0.f ? e : 1.f;
            a = f1 * a + f2 * vv;
            b = f1 * b + f2;
            p = fmaxf(pw, kk);
        }
#pragma unroll
        for (int j = 0; j < 8; ++j) { kq[j] = kn[j]; vq[j] = vn[j]; }
        idx += 8 * stride;
    }
    const int sidx = (((dir * GCH + g) * 8 + bt) << 10) + c;
    sumA[sidx] = a; sumB[sidx] = b; sumP[sidx] = p;
}

// ---------------------------------------------------------------------------
// Phase 2 fused: per row-chunk g, compute BOTH directions (fwd chunk g and
// bwd chunk GCH-1-g cover the same rows). Pass 1: fwd outputs -> LDS.
// Pass 2: bwd outputs + combine with sigmoid(r_pre), write bf16 rwkv.
// grid (16, B, GCH), 64 thr. 16 KB LDS/block.
// ---------------------------------------------------------------------------
__global__ __launch_bounds__(64)
void wkv_out2(const u16* __restrict__ kbuf, const u16* __restrict__ vbuf,
              const float* __restrict__ decay, const float* __restrict__ uarr,
              const float* __restrict__ sumA, const float* __restrict__ sumB,
              const float* __restrict__ sumP,
              const u16* __restrict__ rpre, u16* __restrict__ rwkv)
{
    __shared__ float fbuf[TCH * 64];
    const int lane = threadIdx.x;
    const int c   = blockIdx.x * 64 + lane;
    const int bt  = blockIdx.y;
    const int g   = blockIdx.z;
    const long base = (long)bt * (1024 * 1024) + c;
    const long rowBase = base + (long)(g * TCH) * 1024;
    const float w  = -__expf(decay[c]);
    const float uu = uarr[c];

    // ---- pass 1: forward (ascending t), outputs to LDS ----
    {
        float a = 0.f, b = 0.f, p = -1e38f;
        for (int gg = 0; gg < g; ++gg) {
            const int sidx = ((gg * 8 + bt) << 10) + c;
            const float a2 = sumA[sidx], b2 = sumB[sidx], p2 = sumP[sidx];
            const float pd = p + w * (float)TCH;
            const float d  = pd - p2;
            const float e  = __expf(-fabsf(d));
            const float x1 = d >= 0.f ? 1.f : e;
            const float x2 = d >= 0.f ? e : 1.f;
            a = x1 * a + x2 * a2;
            b = x1 * b + x2 * b2;
            p = fmaxf(pd, p2);
        }
        long idx = rowBase;
        float kq[8], vq[8];
#pragma unroll
        for (int j = 0; j < 8; ++j) {
            kq[j] = bf2f(kbuf[idx + j * 1024]);
            vq[j] = bf2f(vbuf[idx + j * 1024]);
        }
        for (int tb = 0; tb < TCH / 8; ++tb) {
            float kn[8], vn[8];
            if (tb < TCH / 8 - 1) {
#pragma unroll
                for (int j = 0; j < 8; ++j) {
                    kn[j] = bf2f(kbuf[idx + (j + 8) * 1024]);
                    vn[j] = bf2f(vbuf[idx + (j + 8) * 1024]);
                }
            }
#pragma unroll
            for (int j = 0; j < 8; ++j) {
                const float kk = kq[j], vv = vq[j];
                const float uk = uu + kk;
                const float d1 = p - uk;
                const float e  = __expf(-fabsf(d1));
                const float e1 = d1 >= 0.f ? 1.f : e;
                const float e2 = d1 >= 0.f ? e : 1.f;
                fbuf[(tb * 8 + j) * 64 + lane] =
                    __fdividef(e1 * a + e2 * vv, e1 * b + e2);
                const float pw = p + w;
                const float d2 = pw - kk;
                const float e_ = __expf(-fabsf(d2));
                const float f1 = d2 >= 0.f ? 1.f : e_;
                const float f2 = d2 >= 0.f ? e_ : 1.f;
                a = f1 * a + f2 * vv;
                b = f1 * b + f2;
                p = fmaxf(pw, kk);
            }
#pragma unroll
            for (int j = 0; j < 8; ++j) { kq[j] = kn[j]; vq[j] = vn[j]; }
            idx += 8 * 1024;
        }
    }
    __syncthreads();

    // ---- pass 2: backward (descending t), combine + write ----
    {
        float a = 0.f, b = 0.f, p = -1e38f;
        const int gb = GCH - 1 - g;   // this chunk's index in bwd order
        for (int gg = 0; gg < gb; ++gg) {
            const int sidx = (((GCH + gg) * 8 + bt) << 10) + c;
            const float a2 = sumA[sidx], b2 = sumB[sidx], p2 = sumP[sidx];
            const float pd = p + w * (float)TCH;
            const float d  = pd - p2;
            const float e  = __expf(-fabsf(d));
            const float x1 = d >= 0.f ? 1.f : e;
            const float x2 = d >= 0.f ? e : 1.f;
            a = x1 * a + x2 * a2;
            b = x1 * b + x2 * b2;
            p = fmaxf(pd, p2);
        }
        long idx = rowBase + (long)(TCH - 1) * 1024;
        float kq[8], vq[8];
#pragma unroll
        for (int j = 0; j < 8; ++j) {
            kq[j] = bf2f(kbuf[idx - j * 1024]);
            vq[j] = bf2f(vbuf[idx - j * 1024]);
        }
        for (int tb = 0; tb < TCH / 8; ++tb) {
            float kn[8], vn[8];
            if (tb < TCH / 8 - 1) {
#pragma unroll
                for (int j = 0; j < 8; ++j) {
                    kn[j] = bf2f(kbuf[idx - (j + 8) * 1024]);
                    vn[j] = bf2f(vbuf[idx - (j + 8) * 1024]);
                }
            }
#pragma unroll
            for (int j = 0; j < 8; ++j) {
                const long ii = idx - (long)j * 1024;
                const int  tl = TCH - 1 - (tb * 8 + j);
                const float kk = kq[j], vv = vq[j];
                const float uk = uu + kk;
                const float d1 = p - uk;
                const float e  = __expf(-fabsf(d1));
                const float e1 = d1 >= 0.f ? 1.f : e;
                const float e2 = d1 >= 0.f ? e : 1.f;
                const float ob = __fdividef(e1 * a + e2 * vv, e1 * b + e2);
                const float of = fbuf[tl * 64 + lane];
                const float rr = __fdividef(1.f, 1.f + __expf(-bf2f(rpre[ii])));
                rwkv[ii] = f2bf(rr * 0.5f * (of + ob));
                const float pw = p + w;
                const float d2 = pw - kk;
                const float e_ = __expf(-fabsf(d2));
                const float f1 = d2 >= 0.f ? 1.f : e_;
                const float f2 = d2 >= 0.f ? e_ : 1.f;
                a = f1 * a + f2 * vv;
                b = f1 * b + f2;
                p = fmaxf(pw, kk);
            }
#pragma unroll
            for (int j = 0; j < 8; ++j) { kq[j] = kn[j]; vq[j] = vn[j]; }
            idx -= 8 * 1024;
        }
    }
}

// ---------------------------------------------------------------------------
extern "C" void kernel_launch(void* const* d_in, const int* in_sizes, int n_in,
                              void* d_out, int out_size, void* d_ws, size_t ws_size,
                              hipStream_t stream)
{
    (void)in_sizes; (void)n_in; (void)out_size; (void)ws_size;
    const float* x     = (const float*)d_in[0];
    const float* ln1w  = (const float*)d_in[1];
    const float* ln1b  = (const float*)d_in[2];
    const float* ln2w  = (const float*)d_in[3];
    const float* ln2b  = (const float*)d_in[4];
    const float* Wr    = (const float*)d_in[5];
    const float* Wk    = (const float*)d_in[6];
    const float* Wv    = (const float*)d_in[7];
    const float* Wo    = (const float*)d_in[8];
    const float* decay = (const float*)d_in[9];
    const float* uarr  = (const float*)d_in[10];
    const float* Wfk   = (const float*)d_in[11];
    const float* Wfv   = (const float*)d_in[12];
    const float* Wfr   = (const float*)d_in[13];

    const int M = 8192, C = 1024, C4 = 4096;
    const size_t MB = 1024u * 1024u;
    char* ws = (char*)d_ws;
    u16*  X2    = (u16*)(ws);                // [0,16)    x after time-mix (bf16)
    u16*  XN    = (u16*)(ws + 16 * MB);      // [16,32)   xn / xn2
    u16*  RP    = (u16*)(ws + 32 * MB);      // [32,48)   r_pre, later ffn sigmoid
    u16*  KB    = (u16*)(ws + 48 * MB);      // [48,64)   k
    u16*  VB    = (u16*)(ws + 64 * MB);      // [64,80)   v
    u16*  RWKV  = (u16*)(ws + 80 * MB);      // [80,96)   combined rwkv
    u16*  KK    = (u16*)(ws + 48 * MB);      // [48,112)  ffn relu^2 key (reuse)
    float* sumA = (float*)(ws + 112 * MB);   // 1 MB each
    float* sumB = (float*)(ws + 113 * MB);
    float* sumP = (float*)(ws + 114 * MB);
    // bf16 weights: [Wr;Wk;Wv] contiguous, [Wfk;Wfr] contiguous
    u16*  WrB   = (u16*)(ws + 116 * MB);     // 2 MB
    u16*  WkB   = (u16*)(ws + 118 * MB);     // 2 MB
    u16*  WvB   = (u16*)(ws + 120 * MB);     // 2 MB
    u16*  WoB   = (u16*)(ws + 122 * MB);     // 2 MB
    u16*  WfkB  = (u16*)(ws + 124 * MB);     // 8 MB
    u16*  WfrB  = (u16*)(ws + 132 * MB);     // 2 MB
    u16*  WfvB  = (u16*)(ws + 134 * MB);     // 8 MB -> ends 142 MB

    const dim3 blk(256);
    const int n4_1M = C * C / 4, n4_4M = C * C4 / 4;

    F2BFSegs segs;
    segs.src[0] = Wr;  segs.dst[0] = WrB;  segs.n4[0] = n4_1M;
    segs.src[1] = Wk;  segs.dst[1] = WkB;  segs.n4[1] = n4_1M;
    segs.src[2] = Wv;  segs.dst[2] = WvB;  segs.n4[2] = n4_1M;
    segs.src[3] = Wo;  segs.dst[3] = WoB;  segs.n4[3] = n4_1M;
    segs.src[4] = Wfk; segs.dst[4] = WfkB; segs.n4[4] = n4_4M;
    segs.src[5] = Wfr; segs.dst[5] = WfrB; segs.n4[5] = n4_1M;
    segs.src[6] = Wfv; segs.dst[6] = WfvB; segs.n4[6] = n4_4M;
    f2bf_all<<<dim3(n4_4M / 256, 7), blk, 0, stream>>>(segs);

    ln_kernel<0><<<dim3(M), blk, 0, stream>>>(x, ln1w, ln1b, XN);
    // fused QKV: N = 3072, B = [Wr;Wk;Wv]
    gemm_bt<5><<<dim3(M / 128, 3 * C / 128), blk, 0, stream>>>(
        XN, WrB, M, 3 * C, C, RP, KB, VB);
    wkv_sum<<<dim3(16, 8, 2 * GCH), dim3(64), 0, stream>>>(KB, VB, decay,
                                                           sumA, sumB, sumP);
    wkv_out2<<<dim3(16, 8, GCH), dim3(64), 0, stream>>>(KB, VB, decay, uarr,
                                                        sumA, sumB, sumP,
                                                        RP, RWKV);
    gemm_bt<1><<<dim3(M / 128, C / 128), blk, 0, stream>>>(
        RWKV, WoB, M, C, C, X2, x, nullptr);
    ln_kernel<1><<<dim3(M), blk, 0, stream>>>(X2, ln2w, ln2b, XN);
    // fused FFN-in: N = 5120, B = [Wfk;Wfr]; relu^2 -> KK, sigmoid -> RP
    gemm_bt<6><<<dim3(M / 128, 5 * C / 128), blk, 0, stream>>>(
        XN, WfkB, M, 5 * C, C, KK, RP, nullptr);
    gemm_bt<4><<<dim3(M / 128, C / 128), blk, 0, stream>>>(
        KK, WfvB, M, C, C4, d_out, X2, RP);
}

// Round 7
// 411.476 us; speedup vs baseline: 1.5845x; 1.1230x over previous
//
#include <hip/hip_runtime.h>
#include <cstdint>
#include <cstddef>

typedef unsigned short u16;
typedef unsigned char u8;
typedef unsigned int u32;
typedef __bf16 bf16_t;
typedef bf16_t bf16x8 __attribute__((ext_vector_type(8)));
typedef float f32x4 __attribute__((ext_vector_type(4)));
typedef int i32x8 __attribute__((ext_vector_type(8)));

#define GCH 16          // scan chunks
#define TCH 64          // steps per chunk (1024 / GCH)

static __device__ __forceinline__ float bf2f(u16 v) {
    union { unsigned int u; float f; } cv;
    cv.u = ((unsigned int)v) << 16;
    return cv.f;
}
static __device__ __forceinline__ u16 f2bf(float f) {
    union { float f; unsigned int u; } cv;
    cv.f = f;
    unsigned int r = 0x7fffu + ((cv.u >> 16) & 1u);
    return (u16)((cv.u + r) >> 16);
}

// ---------------------------------------------------------------------------
// weight conversion: mode 0 = fp32->bf16; mode 1 = fp32->fp8 e4m3 of (w*16)
// (x16 prescale keeps N(0,0.02) weights out of e4m3 subnormals; compensated
//  in hardware by MFMA scale_b = 2^-4). grid (blocks, 7).
// ---------------------------------------------------------------------------
struct WSegs { const float* src[7]; void* dst[7]; int n4[7]; int mode[7]; };

__global__ __launch_bounds__(256)
void wconv_all(WSegs s)
{
    const int seg = blockIdx.y;
    const int i = blockIdx.x * 256 + threadIdx.x;
    if (i >= s.n4[seg]) return;
    float4 f = ((const float4*)s.src[seg])[i];
    if (s.mode[seg] == 0) {
        ushort4 o;
        o.x = f2bf(f.x); o.y = f2bf(f.y); o.z = f2bf(f.z); o.w = f2bf(f.w);
        ((ushort4*)s.dst[seg])[i] = o;
    } else {
        const int p0 = __builtin_amdgcn_cvt_pk_fp8_f32(f.x * 16.f, f.y * 16.f, 0, 0);
        const int p1 = __builtin_amdgcn_cvt_pk_fp8_f32(f.z * 16.f, f.w * 16.f, 0, 0);
        ((u32*)s.dst[seg])[i] = (u32)(p0 & 0xFFFF) | ((u32)p1 << 16);
    }
}

// ---------------------------------------------------------------------------
// LayerNorm rows of 1024. IN: 0=fp32, 1=bf16. OUT8: 0=bf16 out, 1=fp8 out.
// ---------------------------------------------------------------------------
template<int BF16IN, int OUT8>
__global__ __launch_bounds__(256)
void ln_kernel(const void* __restrict__ xin, const float* __restrict__ w,
               const float* __restrict__ b, void* __restrict__ out)
{
    const int row = blockIdx.x;
    const int tid = threadIdx.x;
    float vals[4];
    if (BF16IN) {
        const ushort4 uv = ((const ushort4*)((const u16*)xin + (size_t)row * 1024))[tid];
        vals[0] = bf2f(uv.x); vals[1] = bf2f(uv.y);
        vals[2] = bf2f(uv.z); vals[3] = bf2f(uv.w);
    } else {
        const float4 f = ((const float4*)((const float*)xin + (size_t)row * 1024))[tid];
        vals[0] = f.x; vals[1] = f.y; vals[2] = f.z; vals[3] = f.w;
    }
    float s  = vals[0] + vals[1] + vals[2] + vals[3];
    float ss = vals[0]*vals[0] + vals[1]*vals[1] + vals[2]*vals[2] + vals[3]*vals[3];
    for (int off = 32; off; off >>= 1) {
        s  += __shfl_down(s, off, 64);
        ss += __shfl_down(ss, off, 64);
    }
    __shared__ float redS[4], redQ[4];
    if ((tid & 63) == 0) { redS[tid >> 6] = s; redQ[tid >> 6] = ss; }
    __syncthreads();
    s  = redS[0] + redS[1] + redS[2] + redS[3];
    ss = redQ[0] + redQ[1] + redQ[2] + redQ[3];
    const float mu  = s * (1.f / 1024.f);
    const float var = ss * (1.f / 1024.f) - mu * mu;
    const float rs  = rsqrtf(var + 1e-5f);
    const float4 wv = ((const float4*)w)[tid];
    const float4 bv = ((const float4*)b)[tid];
    const float o0 = (vals[0] - mu) * rs * wv.x + bv.x;
    const float o1 = (vals[1] - mu) * rs * wv.y + bv.y;
    const float o2 = (vals[2] - mu) * rs * wv.z + bv.z;
    const float o3 = (vals[3] - mu) * rs * wv.w + bv.w;
    if (OUT8) {
        const int p0 = __builtin_amdgcn_cvt_pk_fp8_f32(o0, o1, 0, 0);
        const int p1 = __builtin_amdgcn_cvt_pk_fp8_f32(o2, o3, 0, 0);
        ((u32*)out)[(size_t)row * 256 + tid] = (u32)(p0 & 0xFFFF) | ((u32)p1 << 16);
    } else {
        ushort4 o;
        o.x = f2bf(o0); o.y = f2bf(o1); o.z = f2bf(o2); o.w = f2bf(o3);
        ((ushort4*)out)[(size_t)row * 256 + tid] = o;
    }
}

// ---------------------------------------------------------------------------
// bf16 GEMM: out[M,N] = A[M,K] @ B[N,K]^T, m97 recipe + XOR swizzle +
// transposed grid (x = M-panel for XCD L2 locality).
// EPI: 1: bf16(f32(aux1)+acc); 4: f32: bf16(aux1)+bf16(aux2)*acc -> float;
//      5: QKV fused split (N=3072): seg0->outp, seg1->aux1, seg2->aux2
// ---------------------------------------------------------------------------
template<int EPI>
__global__ __launch_bounds__(256)
void gemm_bt(const u16* __restrict__ A, const u16* __restrict__ B,
             int M, int N, int K,
             void* __restrict__ outp,
             const void* __restrict__ aux1, const void* __restrict__ aux2)
{
    __shared__ u16 lA[128 * 64];
    __shared__ u16 lB[128 * 64];
    const int tid  = threadIdx.x;
    const int wave = tid >> 6;
    const int lane = tid & 63;
    const int q    = lane >> 4;
    const int l16  = lane & 15;
    const long mBase = (long)blockIdx.x * 128;
    const long nBase = (long)blockIdx.y * 128;
    const int wm = (wave >> 1) * 64;
    const int wn = (wave & 1) * 64;

    f32x4 acc[4][4];
#pragma unroll
    for (int i = 0; i < 4; ++i)
#pragma unroll
        for (int j = 0; j < 4; ++j)
#pragma unroll
            for (int r = 0; r < 4; ++r) acc[i][j][r] = 0.f;

    const int srow = tid >> 3;
    const int scol = ((tid & 7) ^ (srow & 7)) * 8;
    const int ldsW = wave * 512;
    const int swz = l16 & 7;

    for (int kb = 0; kb < K; kb += 64) {
        __syncthreads();
#pragma unroll
        for (int c = 0; c < 4; ++c) {
            const int row = c * 32 + srow;
            const u16* ga = A + (mBase + row) * (long)K + kb + scol;
            const u16* gb = B + (nBase + row) * (long)K + kb + scol;
            __builtin_amdgcn_global_load_lds(
                (const __attribute__((address_space(1))) void*)ga,
                (__attribute__((address_space(3))) void*)(lA + c * 2048 + ldsW),
                16, 0, 0);
            __builtin_amdgcn_global_load_lds(
                (const __attribute__((address_space(1))) void*)gb,
                (__attribute__((address_space(3))) void*)(lB + c * 2048 + ldsW),
                16, 0, 0);
        }
        __syncthreads();
#pragma unroll
        for (int ks = 0; ks < 2; ++ks) {
            const int grp = ((ks * 4 + q) ^ swz) * 8;
            bf16x8 af[4], bfm[4];
#pragma unroll
            for (int i = 0; i < 4; ++i) {
                af[i]  = *(const bf16x8*)(lA + (wm + i * 16 + l16) * 64 + grp);
                bfm[i] = *(const bf16x8*)(lB + (wn + i * 16 + l16) * 64 + grp);
            }
#pragma unroll
            for (int i = 0; i < 4; ++i)
#pragma unroll
                for (int j = 0; j < 4; ++j)
                    acc[i][j] = __builtin_amdgcn_mfma_f32_16x16x32_bf16(
                        af[i], bfm[j], acc[i][j], 0, 0, 0);
        }
    }

    if (EPI == 5) {
        const long seg = nBase >> 10;
        u16* optr = (u16*)(seg == 0 ? outp : seg == 1 ? (void*)aux1 : (void*)aux2);
        const long cb = (nBase & 1023) + wn + l16;
#pragma unroll
        for (int i = 0; i < 4; ++i)
#pragma unroll
            for (int r = 0; r < 4; ++r) {
                const long rowOff = (mBase + wm + i * 16 + q * 4 + r) * 1024 + cb;
#pragma unroll
                for (int j = 0; j < 4; ++j)
                    optr[rowOff + j * 16] = f2bf(acc[i][j][r]);
            }
    } else {
        const long colBase = nBase + wn + l16;
#pragma unroll
        for (int i = 0; i < 4; ++i) {
#pragma unroll
            for (int r = 0; r < 4; ++r) {
                const long row = mBase + wm + i * 16 + q * 4 + r;
                const long rowOff = row * (long)N;
#pragma unroll
                for (int j = 0; j < 4; ++j) {
                    const long idx = rowOff + colBase + j * 16;
                    const float val = acc[i][j][r];
                    if (EPI == 1) {
                        ((u16*)outp)[idx] = f2bf(((const float*)aux1)[idx] + val);
                    } else {
                        const float t = bf2f(((const u16*)aux1)[idx])
                                      + bf2f(((const u16*)aux2)[idx]) * val;
                        ((float*)outp)[idx] = t;
                    }
                }
            }
        }
    }
}

// ---------------------------------------------------------------------------
// fp8-MX GEMM (FFN-in): out = A[M,K]fp8 @ B[N,K]^T fp8, K=1024, N=5120.
// mfma_scale_f32_16x16x128_f8f6f4, BK=128 bytes, 128-B LDS rows, XOR swizzle
// on 16-B units. scale_a=127 (x1, activations), scale_b=123 (x2^-4,
// compensates weight x16 prescale). Epilogue: n<4096: relu^2 -> kk bf16
// (stride 4096); else sigmoid -> rp bf16 (stride 1024).
// ---------------------------------------------------------------------------
__global__ __launch_bounds__(256)
void gemm_f8(const u8* __restrict__ A, const u8* __restrict__ B,
             int M, int N, int K,
             u16* __restrict__ kk, u16* __restrict__ rp)
{
    __shared__ __align__(16) u8 lA[128 * 128];
    __shared__ __align__(16) u8 lB[128 * 128];
    const int tid  = threadIdx.x;
    const int wave = tid >> 6;
    const int lane = tid & 63;
    const int q    = lane >> 4;
    const int l16  = lane & 15;
    const long mBase = (long)blockIdx.x * 128;
    const long nBase = (long)blockIdx.y * 128;
    const int wm = (wave >> 1) * 64;
    const int wn = (wave & 1) * 64;

    f32x4 acc[4][4];
#pragma unroll
    for (int i = 0; i < 4; ++i)
#pragma unroll
        for (int j = 0; j < 4; ++j)
#pragma unroll
            for (int r = 0; r < 4; ++r) acc[i][j][r] = 0.f;

    const int srow  = tid >> 3;                       // 8 lanes per 128-B row
    const int scolB = ((tid & 7) ^ (srow & 7)) * 16;  // swizzled 16-B unit
    const int ldsW  = wave * 1024;
    const int swz   = l16 & 7;

    for (int kb = 0; kb < K; kb += 128) {
        __syncthreads();
#pragma unroll
        for (int c = 0; c < 4; ++c) {
            const int row = c * 32 + srow;
            const u8* ga = A + (mBase + row) * (long)K + kb + scolB;
            const u8* gb = B + (nBase + row) * (long)K + kb + scolB;
            __builtin_amdgcn_global_load_lds(
                (const __attribute__((address_space(1))) void*)ga,
                (__attribute__((address_space(3))) void*)(lA + c * 4096 + ldsW),
                16, 0, 0);
            __builtin_amdgcn_global_load_lds(
                (const __attribute__((address_space(1))) void*)gb,
                (__attribute__((address_space(3))) void*)(lB + c * 4096 + ldsW),
                16, 0, 0);
        }
        __syncthreads();
        // fragment: lane reads 32 B = 16-B units {2q, 2q+1} XOR swz.
        // XOR flips only unit bit0 within an aligned pair; the resulting
        // k-halves swap identically on A and B (same swz per lane) -> exact.
        const int u0 = ((2 * q) ^ swz) * 16;
        const int u1 = ((2 * q + 1) ^ swz) * 16;
        i32x8 af[4], bfm[4];
#pragma unroll
        for (int i = 0; i < 4; ++i) {
            {
                const u8* base = lA + (wm + i * 16 + l16) * 128;
                const uint4 lo = *(const uint4*)(base + u0);
                const uint4 hi = *(const uint4*)(base + u1);
                af[i][0] = lo.x; af[i][1] = lo.y; af[i][2] = lo.z; af[i][3] = lo.w;
                af[i][4] = hi.x; af[i][5] = hi.y; af[i][6] = hi.z; af[i][7] = hi.w;
            }
            {
                const u8* base = lB + (wn + i * 16 + l16) * 128;
                const uint4 lo = *(const uint4*)(base + u0);
                const uint4 hi = *(const uint4*)(base + u1);
                bfm[i][0] = lo.x; bfm[i][1] = lo.y; bfm[i][2] = lo.z; bfm[i][3] = lo.w;
                bfm[i][4] = hi.x; bfm[i][5] = hi.y; bfm[i][6] = hi.z; bfm[i][7] = hi.w;
            }
        }
#pragma unroll
        for (int i = 0; i < 4; ++i)
#pragma unroll
            for (int j = 0; j < 4; ++j)
                acc[i][j] = __builtin_amdgcn_mfma_scale_f32_16x16x128_f8f6f4(
                    af[i], bfm[j], acc[i][j], 0, 0, 0, 127, 0, 123);
    }

    // epilogue (C/D layout: col=lane&15, row=quad*4+reg — shape-determined)
    u16* optr; long sN, cb;
    if (nBase < 4096) { optr = kk; sN = 4096; cb = nBase + wn + l16; }
    else              { optr = rp; sN = 1024; cb = (nBase - 4096) + wn + l16; }
#pragma unroll
    for (int i = 0; i < 4; ++i)
#pragma unroll
        for (int r = 0; r < 4; ++r) {
            const long rowOff = (mBase + wm + i * 16 + q * 4 + r) * sN + cb;
#pragma unroll
            for (int j = 0; j < 4; ++j) {
                const float val = acc[i][j][r];
                float t;
                if (nBase < 4096) t = val > 0.f ? val * val : 0.f;
                else t = __fdividef(1.f, 1.f + __expf(-val));
                optr[rowOff + j * 16] = f2bf(t);
            }
        }
}

// ---------------------------------------------------------------------------
// Chunked WKV scan, phase 1: per-chunk (a,b,p) summary, both dirs.
// ---------------------------------------------------------------------------
__global__ __launch_bounds__(64)
void wkv_sum(const u16* __restrict__ kbuf, const u16* __restrict__ vbuf,
             const float* __restrict__ decay,
             float* __restrict__ sumA, float* __restrict__ sumB,
             float* __restrict__ sumP)
{
    const int c   = blockIdx.x * 64 + threadIdx.x;
    const int bt  = blockIdx.y;
    const int dir = blockIdx.z & 1;
    const int g   = blockIdx.z >> 1;
    const long base = (long)bt * (1024 * 1024) + c;
    const long stride = dir ? -1024 : 1024;
    long idx = dir ? base + (long)(1023 - g * TCH) * 1024
                   : base + (long)(g * TCH) * 1024;
    const float w = -__expf(decay[c]);
    float a = 0.f, b = 0.f, p = -1e38f;

    float kq[8], vq[8];
#pragma unroll
    for (int j = 0; j < 8; ++j) {
        kq[j] = bf2f(kbuf[idx + j * stride]);
        vq[j] = bf2f(vbuf[idx + j * stride]);
    }
    for (int tb = 0; tb < TCH / 8; ++tb) {
        float kn[8], vn[8];
        if (tb < TCH / 8 - 1) {
#pragma unroll
            for (int j = 0; j < 8; ++j) {
                kn[j] = bf2f(kbuf[idx + (j + 8) * stride]);
                vn[j] = bf2f(vbuf[idx + (j + 8) * stride]);
            }
        }
#pragma unroll
        for (int j = 0; j < 8; ++j) {
            const float kk = kq[j], vv = vq[j];
            const float pw = p + w;
            const float d  = pw - kk;
            const float e  = __expf(-fabsf(d));
            const float f1 = d >= 0.f ? 1.f : e;
            const float f2 = d >= 0.f ? e : 1.f;
            a = f1 * a + f2 * vv;
            b = f1 * b + f2;
            p = fmaxf(pw, kk);
        }
#pragma unroll
        for (int j = 0; j < 8; ++j) { kq[j] = kn[j]; vq[j] = vn[j]; }
        idx += 8 * stride;
    }
    const int sidx = (((dir * GCH + g) * 8 + bt) << 10) + c;
    sumA[sidx] = a; sumB[sidx] = b; sumP[sidx] = p;
}

// ---------------------------------------------------------------------------
// Phase 2 fused: fwd pass -> LDS, bwd pass + sigmoid(r)*0.5*(f+b) -> bf16.
// ---------------------------------------------------------------------------
__global__ __launch_bounds__(64)
void wkv_out2(const u16* __restrict__ kbuf, const u16* __restrict__ vbuf,
              const float* __restrict__ decay, const float* __restrict__ uarr,
              const float* __restrict__ sumA, const float* __restrict__ sumB,
              const float* __restrict__ sumP,
              const u16* __restrict__ rpre, u16* __restrict__ rwkv)
{
    __shared__ float fbuf[TCH * 64];
    const int lane = threadIdx.x;
    const int c   = blockIdx.x * 64 + lane;
    const int bt  = blockIdx.y;
    const int g   = blockIdx.z;
    const long base = (long)bt * (1024 * 1024) + c;
    const long rowBase = base + (long)(g * TCH) * 1024;
    const float w  = -__expf(decay[c]);
    const float uu = uarr[c];

    {
        float a = 0.f, b = 0.f, p = -1e38f;
        for (int gg = 0; gg < g; ++gg) {
            const int sidx = ((gg * 8 + bt) << 10) + c;
            const float a2 = sumA[sidx], b2 = sumB[sidx], p2 = sumP[sidx];
            const float pd = p + w * (float)TCH;
            const float d  = pd - p2;
            const float e  = __expf(-fabsf(d));
            const float x1 = d >= 0.f ? 1.f : e;
            const float x2 = d >= 0.f ? e : 1.f;
            a = x1 * a + x2 * a2;
            b = x1 * b + x2 * b2;
            p = fmaxf(pd, p2);
        }
        long idx = rowBase;
        float kq[8], vq[8];
#pragma unroll
        for (int j = 0; j < 8; ++j) {
            kq[j] = bf2f(kbuf[idx + j * 1024]);
            vq[j] = bf2f(vbuf[idx + j * 1024]);
        }
        for (int tb = 0; tb < TCH / 8; ++tb) {
            float kn[8], vn[8];
            if (tb < TCH / 8 - 1) {
#pragma unroll
                for (int j = 0; j < 8; ++j) {
                    kn[j] = bf2f(kbuf[idx + (j + 8) * 1024]);
                    vn[j] = bf2f(vbuf[idx + (j + 8) * 1024]);
                }
            }
#pragma unroll
            for (int j = 0; j < 8; ++j) {
                const float kk = kq[j], vv = vq[j];
                const float uk = uu + kk;
                const float d1 = p - uk;
                const float e  = __expf(-fabsf(d1));
                const float e1 = d1 >= 0.f ? 1.f : e;
                const float e2 = d1 >= 0.f ? e : 1.f;
                fbuf[(tb * 8 + j) * 64 + lane] =
                    __fdividef(e1 * a + e2 * vv, e1 * b + e2);
                const float pw = p + w;
                const float d2 = pw - kk;
                const float e_ = __expf(-fabsf(d2));
                const float f1 = d2 >= 0.f ? 1.f : e_;
                const float f2 = d2 >= 0.f ? e_ : 1.f;
                a = f1 * a + f2 * vv;
                b = f1 * b + f2;
                p = fmaxf(pw, kk);
            }
#pragma unroll
            for (int j = 0; j < 8; ++j) { kq[j] = kn[j]; vq[j] = vn[j]; }
            idx += 8 * 1024;
        }
    }
    __syncthreads();

    {
        float a = 0.f, b = 0.f, p = -1e38f;
        const int gb = GCH - 1 - g;
        for (int gg = 0; gg < gb; ++gg) {
            const int sidx = (((GCH + gg) * 8 + bt) << 10) + c;
            const float a2 = sumA[sidx], b2 = sumB[sidx], p2 = sumP[sidx];
            const float pd = p + w * (float)TCH;
            const float d  = pd - p2;
            const float e  = __expf(-fabsf(d));
            const float x1 = d >= 0.f ? 1.f : e;
            const float x2 = d >= 0.f ? e : 1.f;
            a = x1 * a + x2 * a2;
            b = x1 * b + x2 * b2;
            p = fmaxf(pd, p2);
        }
        long idx = rowBase + (long)(TCH - 1) * 1024;
        float kq[8], vq[8];
#pragma unroll
        for (int j = 0; j < 8; ++j) {
            kq[j] = bf2f(kbuf[idx - j * 1024]);
            vq[j] = bf2f(vbuf[idx - j * 1024]);
        }
        for (int tb = 0; tb < TCH / 8; ++tb) {
            float kn[8], vn[8];
            if (tb < TCH / 8 - 1) {
#pragma unroll
                for (int j = 0; j < 8; ++j) {
                    kn[j] = bf2f(kbuf[idx - (j + 8) * 1024]);
                    vn[j] = bf2f(vbuf[idx - (j + 8) * 1024]);
                }
            }
#pragma unroll
            for (int j = 0; j < 8; ++j) {
                const long ii = idx - (long)j * 1024;
                const int  tl = TCH - 1 - (tb * 8 + j);
                const float kk = kq[j], vv = vq[j];
                const float uk = uu + kk;
                const float d1 = p - uk;
                const float e  = __expf(-fabsf(d1));
                const float e1 = d1 >= 0.f ? 1.f : e;
                const float e2 = d1 >= 0.f ? e : 1.f;
                const float ob = __fdividef(e1 * a + e2 * vv, e1 * b + e2);
                const float of = fbuf[tl * 64 + lane];
                const float rr = __fdividef(1.f, 1.f + __expf(-bf2f(rpre[ii])));
                rwkv[ii] = f2bf(rr * 0.5f * (of + ob));
                const float pw = p + w;
                const float d2 = pw - kk;
                const float e_ = __expf(-fabsf(d2));
                const float f1 = d2 >= 0.f ? 1.f : e_;
                const float f2 = d2 >= 0.f ? e_ : 1.f;
                a = f1 * a + f2 * vv;
                b = f1 * b + f2;
                p = fmaxf(pw, kk);
            }
#pragma unroll
            for (int j = 0; j < 8; ++j) { kq[j] = kn[j]; vq[j] = vn[j]; }
            idx -= 8 * 1024;
        }
    }
}

// ---------------------------------------------------------------------------
extern "C" void kernel_launch(void* const* d_in, const int* in_sizes, int n_in,
                              void* d_out, int out_size, void* d_ws, size_t ws_size,
                              hipStream_t stream)
{
    (void)in_sizes; (void)n_in; (void)out_size; (void)ws_size;
    const float* x     = (const float*)d_in[0];
    const float* ln1w  = (const float*)d_in[1];
    const float* ln1b  = (const float*)d_in[2];
    const float* ln2w  = (const float*)d_in[3];
    const float* ln2b  = (const float*)d_in[4];
    const float* Wr    = (const float*)d_in[5];
    const float* Wk    = (const float*)d_in[6];
    const float* Wv    = (const float*)d_in[7];
    const float* Wo    = (const float*)d_in[8];
    const float* decay = (const float*)d_in[9];
    const float* uarr  = (const float*)d_in[10];
    const float* Wfk   = (const float*)d_in[11];
    const float* Wfv   = (const float*)d_in[12];
    const float* Wfr   = (const float*)d_in[13];

    const int M = 8192, C = 1024, C4 = 4096;
    const size_t MB = 1024u * 1024u;
    char* ws = (char*)d_ws;
    u16*  X2    = (u16*)(ws);                // [0,16)    x after time-mix (bf16)
    u16*  XN    = (u16*)(ws + 16 * MB);      // [16,32)   xn1 bf16
    u8*   XN8   = (u8*)(ws + 16 * MB);       // [16,24)   xn2 fp8 (reuse, xn1 dead)
    u16*  RP    = (u16*)(ws + 32 * MB);      // [32,48)   r_pre, later ffn sigmoid
    u16*  KB    = (u16*)(ws + 48 * MB);      // [48,64)   k
    u16*  VB    = (u16*)(ws + 64 * MB);      // [64,80)   v
    u16*  RWKV  = (u16*)(ws + 80 * MB);      // [80,96)   combined rwkv
    u16*  KK    = (u16*)(ws + 48 * MB);      // [48,112)  ffn relu^2 key (reuse)
    float* sumA = (float*)(ws + 112 * MB);
    float* sumB = (float*)(ws + 113 * MB);
    float* sumP = (float*)(ws + 114 * MB);
    u16*  WrB   = (u16*)(ws + 116 * MB);     // bf16 [Wr;Wk;Wv] contiguous
    u16*  WkB   = (u16*)(ws + 118 * MB);
    u16*  WvB   = (u16*)(ws + 120 * MB);
    u16*  WoB   = (u16*)(ws + 122 * MB);
    u8*   Wf8   = (u8*)(ws + 124 * MB);      // fp8 [Wfk;Wfr] x16, 5 MB
    u8*   Wfr8  = (u8*)(ws + 128 * MB);
    u16*  WfvB  = (u16*)(ws + 130 * MB);     // bf16 8 MB -> ends 138 MB

    const dim3 blk(256);
    const int n4_1M = C * C / 4, n4_4M = C * C4 / 4;

    WSegs segs;
    segs.src[0] = Wr;  segs.dst[0] = WrB;  segs.n4[0] = n4_1M; segs.mode[0] = 0;
    segs.src[1] = Wk;  segs.dst[1] = WkB;  segs.n4[1] = n4_1M; segs.mode[1] = 0;
    segs.src[2] = Wv;  segs.dst[2] = WvB;  segs.n4[2] = n4_1M; segs.mode[2] = 0;
    segs.src[3] = Wo;  segs.dst[3] = WoB;  segs.n4[3] = n4_1M; segs.mode[3] = 0;
    segs.src[4] = Wfk; segs.dst[4] = Wf8;  segs.n4[4] = n4_4M; segs.mode[4] = 1;
    segs.src[5] = Wfr; segs.dst[5] = Wfr8; segs.n4[5] = n4_1M; segs.mode[5] = 1;
    segs.src[6] = Wfv; segs.dst[6] = WfvB; segs.n4[6] = n4_4M; segs.mode[6] = 0;
    wconv_all<<<dim3(n4_4M / 256, 7), blk, 0, stream>>>(segs);

    ln_kernel<0, 0><<<dim3(M), blk, 0, stream>>>(x, ln1w, ln1b, XN);
    gemm_bt<5><<<dim3(M / 128, 3 * C / 128), blk, 0, stream>>>(
        XN, WrB, M, 3 * C, C, RP, KB, VB);
    wkv_sum<<<dim3(16, 8, 2 * GCH), dim3(64), 0, stream>>>(KB, VB, decay,
                                                           sumA, sumB, sumP);
    wkv_out2<<<dim3(16, 8, GCH), dim3(64), 0, stream>>>(KB, VB, decay, uarr,
                                                        sumA, sumB, sumP,
                                                        RP, RWKV);
    gemm_bt<1><<<dim3(M / 128, C / 128), blk, 0, stream>>>(
        RWKV, WoB, M, C, C, X2, x, nullptr);
    ln_kernel<1, 1><<<dim3(M), blk, 0, stream>>>(X2, ln2w, ln2b, XN8);
    // fp8-MX fused FFN-in: N = 5120, B = [Wfk;Wfr] fp8 (x16 prescale)
    gemm_f8<<<dim3(M / 128, 5 * C / 128), blk, 0, stream>>>(
        XN8, Wf8, M, 5 * C, C, KK, RP);
    gemm_bt<4><<<dim3(M / 128, C / 128), blk, 0, stream>>>(
        KK, WfvB, M, C, C4, d_out, X2, RP);
}